// Round 12
// baseline (496.667 us; speedup 1.0000x reference)
//
#include <hip/hip_runtime.h>

static constexpr int NU = 100000;
static constexpr int NM = 20000;
static constexpr int NE = 3200000;
static constexpr int NL = 1000000;
static constexpr int FD = 128;
static constexpr int H  = 64;

// bucket geometry
static constexpr int MBK = 16;                    // movies per bucket
static constexpr int UBK = 64;                    // users per bucket
static constexpr int NBM = NM / MBK;              // 1250
static constexpr int NBU = (NU + UBK - 1) / UBK;  // 1563
// fixed bucket capacities (mean 2560/2048, sigma ~51/45 -> +30/+22 sigma slack)
static constexpr int CAP_M = 4096;
static constexpr int CAP_U = 3072;
static constexpr int B3C = 16384;                 // edges per bin block (per side)

typedef __attribute__((ext_vector_type(8))) short short8v;
typedef __attribute__((ext_vector_type(4))) float f32x4;

__device__ __forceinline__ ushort bf16rne(float x) {
  unsigned u = __float_as_uint(x);
  return (ushort)((u + 0x7fffu + ((u >> 16) & 1u)) >> 16);
}

// ---------------- init bucket cursors to fixed-capacity bases ----------------
__global__ void k_binit2(int* __restrict__ bcur_m, int* __restrict__ bcur_u) {
  int i = blockIdx.x * 256 + threadIdx.x;
  if (i < NBM) bcur_m[i] = i * CAP_M;
  if (i < NBU) bcur_u[i] = i * CAP_U;
}

// ---------------- per-side binned ranked scatter (simple 2-pass) ----------------
// movie-side entry: (d&15)<<17 | s      user-side entry: (s&63)<<15 | d
__global__ void __launch_bounds__(256) k_bin3(
    const int* __restrict__ esrc, const int* __restrict__ edst,
    int* __restrict__ bcur_m, int* __restrict__ bcur_u,
    unsigned* __restrict__ pairs_m, unsigned* __restrict__ pairs_u, int nbPerSide) {
  __shared__ int cnt[NBU];    // 6.1 KB (worst side)
  __shared__ int base[NBU];
  int tid = threadIdx.x;
  bool um = (int)blockIdx.x < nbPerSide;
  int cb = um ? blockIdx.x : blockIdx.x - nbPerSide;
  int nbs = um ? NBM : NBU;
  int sh = um ? 4 : 6;
  int* bcur = um ? bcur_m : bcur_u;
  unsigned* pairs = um ? pairs_m : pairs_u;
  const int* keys = um ? edst : esrc;
  const int* vals = um ? esrc : edst;
  int e0 = cb * B3C, e1 = min(e0 + B3C, NE);
  for (int i = tid; i < nbs; i += 256) cnt[i] = 0;
  __syncthreads();
  // pass 1: count buckets (int4 reads, key array only)
  for (int e = e0 + (tid << 2); e < e1; e += 1024) {
    int4 k = *(const int4*)(keys + e);
    atomicAdd(&cnt[k.x >> sh], 1);
    atomicAdd(&cnt[k.y >> sh], 1);
    atomicAdd(&cnt[k.z >> sh], 1);
    atomicAdd(&cnt[k.w >> sh], 1);
  }
  __syncthreads();
  // reserve global space per touched bucket, reset counters to rank
  for (int i = tid; i < nbs; i += 256) {
    int c = cnt[i];
    if (c > 0) base[i] = atomicAdd(&bcur[i], c);
    cnt[i] = 0;
  }
  __syncthreads();
  // pass 2: ranked write
  int lsh = um ? 17 : 15;
  unsigned lmask = um ? 15u : 63u;
  for (int e = e0 + (tid << 2); e < e1; e += 1024) {
    int4 k = *(const int4*)(keys + e);
    int4 v = *(const int4*)(vals + e);
    int ks[4] = {k.x, k.y, k.z, k.w};
    int vs[4] = {v.x, v.y, v.z, v.w};
    #pragma unroll
    for (int j = 0; j < 4; ++j) {
      int b = ks[j] >> sh;
      int r = atomicAdd(&cnt[b], 1);
      pairs[base[b] + r] = (((unsigned)ks[j] & lmask) << lsh) | (unsigned)vs[j];
    }
  }
}

// ---------------- per-bucket counting sort -> gapped per-node CSR ----------------
__global__ void __launch_bounds__(256) k_sortb4(
    const unsigned* __restrict__ pairs_m, const unsigned* __restrict__ pairs_u,
    const int* __restrict__ bcur_m, const int* __restrict__ bcur_u,
    int* __restrict__ st_m, int* __restrict__ dg_m, int* __restrict__ out_m,
    int* __restrict__ st_u, int* __restrict__ dg_u, ushort* __restrict__ out_u) {
  __shared__ int cnt[64];
  __shared__ int cbase[64];
  const unsigned* pairs; const int* bcur; int* start; int* deg;
  int b, npb, shift, cap, n; unsigned mask;
  bool um = (int)blockIdx.x < NBM;
  if (um) {
    pairs = pairs_m; bcur = bcur_m; start = st_m; deg = dg_m;
    b = blockIdx.x; npb = MBK; shift = 17; mask = 0x1FFFFu; cap = CAP_M; n = NM;
  } else {
    pairs = pairs_u; bcur = bcur_u; start = st_u; deg = dg_u;
    b = blockIdx.x - NBM; npb = UBK; shift = 15; mask = 0x7FFFu; cap = CAP_U; n = NU;
  }
  int tid = threadIdx.x;
  if (tid < 64) cnt[tid] = 0;
  __syncthreads();
  int e0 = b * cap, e1 = bcur[b];
  for (int e = e0 + tid; e < e1; e += 256) atomicAdd(&cnt[pairs[e] >> shift], 1);
  __syncthreads();
  if (tid < 64) {
    int c = cnt[tid];
    int v = c;
    #pragma unroll
    for (int off = 1; off < 64; off <<= 1) {
      int t = __shfl_up(v, off, 64);
      if (tid >= off) v += t;
    }
    int basee = e0 + v - c;
    cbase[tid] = basee;
    int node = b * npb + tid;
    if (tid < npb && node < n) { start[node] = basee; deg[node] = c; }
    cnt[tid] = 0;
  }
  __syncthreads();
  for (int e = e0 + tid; e < e1; e += 256) {
    unsigned v = pairs[e];
    int loc = (int)(v >> shift);
    int r = atomicAdd(&cnt[loc], 1);
    if (um) out_m[cbase[loc] + r] = (int)(v & mask);
    else    out_u[cbase[loc] + r] = (ushort)(v & mask);
  }
}

// ---------------- aggregation: wave-per-node, uint4 gather (8 feats x 8 nbrs) ------
#define ACC4(vv)                                                           \
  a0 += __uint_as_float((vv).x << 16); a1 += __uint_as_float((vv).x & 0xffff0000u); \
  a2 += __uint_as_float((vv).y << 16); a3 += __uint_as_float((vv).y & 0xffff0000u); \
  a4 += __uint_as_float((vv).z << 16); a5 += __uint_as_float((vv).z & 0xffff0000u); \
  a6 += __uint_as_float((vv).w << 16); a7 += __uint_as_float((vv).w & 0xffff0000u);

template <typename IdxT, int UN>   // UN groups of 8 neighbors per iteration
__device__ __forceinline__ void agg_node_w8(const ushort* __restrict__ feat,
                                            const IdxT* __restrict__ idxs,
                                            int s, int degn, float* __restrict__ out,
                                            int d, int lane) {
  int f8 = lane & 7, p = lane >> 3;
  int e = s + degn;
  float a0 = 0.f, a1 = 0.f, a2 = 0.f, a3 = 0.f, a4 = 0.f, a5 = 0.f, a6 = 0.f, a7 = 0.f;
  int i = s;
  for (; i + 8 * UN <= e; i += 8 * UN) {
    uint4 v[UN];
    #pragma unroll
    for (int k = 0; k < UN; ++k) {
      int sj = (int)idxs[i + 8 * k + p];
      v[k] = *(const uint4*)(feat + ((size_t)sj << 6) + (f8 << 3));
    }
    #pragma unroll
    for (int k = 0; k < UN; ++k) { ACC4(v[k]) }
  }
  for (; i < e; i += 8) {
    int ii = i + p;
    bool ok = ii < e;
    int sj = (int)idxs[ok ? ii : i];
    uint4 v = *(const uint4*)(feat + ((size_t)sj << 6) + (f8 << 3));
    if (!ok) { v.x = 0u; v.y = 0u; v.z = 0u; v.w = 0u; }
    ACC4(v)
  }
  #pragma unroll
  for (int m = 8; m < 64; m <<= 1) {
    a0 += __shfl_xor(a0, m, 64); a1 += __shfl_xor(a1, m, 64);
    a2 += __shfl_xor(a2, m, 64); a3 += __shfl_xor(a3, m, 64);
    a4 += __shfl_xor(a4, m, 64); a5 += __shfl_xor(a5, m, 64);
    a6 += __shfl_xor(a6, m, 64); a7 += __shfl_xor(a7, m, 64);
  }
  if (p == 0) {
    float inv = 1.f / fmaxf((float)degn, 1.f);
    float4 o0 = make_float4(a0 * inv, a1 * inv, a2 * inv, a3 * inv);
    float4 o1 = make_float4(a4 * inv, a5 * inv, a6 * inv, a7 * inv);
    *(float4*)&out[((size_t)d << 6) + (f8 << 3)] = o0;
    *(float4*)&out[((size_t)d << 6) + (f8 << 3) + 4] = o1;
  }
}

// ---------------- fused mean aggregation (both directions in one grid) ----------------
__global__ void __launch_bounds__(256) k_agg2e(
    int gm,
    const ushort* __restrict__ fM, const int* __restrict__ stM, const int* __restrict__ dgM,
    const int* __restrict__ idxM, float* __restrict__ outM, int nM,
    const ushort* __restrict__ fU, const int* __restrict__ stU, const int* __restrict__ dgU,
    const ushort* __restrict__ idxU, float* __restrict__ outU, int nU) {
  int lane = threadIdx.x & 63;
  if ((int)blockIdx.x < gm) {
    int d = blockIdx.x * 4 + (threadIdx.x >> 6);
    if (d >= nM) return;
    agg_node_w8<int, 8>(fM, idxM, stM[d], dgM[d], outM, d, lane);   // deg mean 160
  } else {
    int d = (blockIdx.x - gm) * 4 + (threadIdx.x >> 6);
    if (d >= nU) return;
    agg_node_w8<ushort, 4>(fU, idxU, stU[d], dgU[d], outU, d, lane); // deg mean 32
  }
}

// ---------------- fused prep: movie proj (16 rows/blk) + user cvt + packw ----------
static constexpr int PB = NM / 16;                // 1250 proj blocks
static constexpr int CB = (NU * H / 4) / 256;     // 6250 cvt blocks (exact)
__global__ void __launch_bounds__(256) k_prep(
    const float* __restrict__ x, const float* __restrict__ w, const float* __restrict__ b,
    float* __restrict__ out, ushort* __restrict__ outh,
    const float* __restrict__ uemb, ushort* __restrict__ uembh,
    const float* __restrict__ w1, ushort* __restrict__ pw) {
  __shared__ float sw[FD * H];    // 32 KB
  __shared__ float sx[16][FD];    // 8 KB
  int tid = threadIdx.x;
  int blk = blockIdx.x;
  if (blk < PB) {
    int r0 = blk * 16;
    #pragma unroll
    for (int it = 0; it < 8; ++it) {
      int idx = tid + it * 256;
      ((float4*)sw)[idx] = ((const float4*)w)[idx];
    }
    #pragma unroll
    for (int it = 0; it < 2; ++it) {
      int idx = tid + it * 256;
      int row = idx >> 5, q = idx & 31;
      *(float4*)&sx[row][q * 4] = ((const float4*)x)[(size_t)(r0 + row) * 32 + q];
    }
    __syncthreads();
    int col = tid & 63, rg = tid >> 6;
    float bb = b[col];
    float acc[4];
    #pragma unroll
    for (int j = 0; j < 4; ++j) acc[j] = bb;
    #pragma unroll 4
    for (int k4 = 0; k4 < 32; ++k4) {
      float w0 = sw[(k4 * 4 + 0) * H + col], w1_ = sw[(k4 * 4 + 1) * H + col];
      float w2 = sw[(k4 * 4 + 2) * H + col], w3 = sw[(k4 * 4 + 3) * H + col];
      #pragma unroll
      for (int j = 0; j < 4; ++j) {
        float4 a = *(const float4*)&sx[rg + j * 4][k4 * 4];
        acc[j] += a.x * w0 + a.y * w1_ + a.z * w2 + a.w * w3;
      }
    }
    #pragma unroll
    for (int j = 0; j < 4; ++j) {
      size_t o = (size_t)(r0 + rg + j * 4) * H + col;
      out[o] = acc[j];
      outh[o] = bf16rne(acc[j]);
    }
  } else if (blk < PB + CB) {
    int i = (blk - PB) * 256 + tid;
    float4 v = ((const float4*)uemb)[i];
    ushort4 o;
    o.x = bf16rne(v.x); o.y = bf16rne(v.y); o.z = bf16rne(v.z); o.w = bf16rne(v.w);
    ((ushort4*)uembh)[i] = o;
  } else {
    for (int it = 0; it < 4; ++it) {
      int q = tid + it * 256;
      int kt = q >> 8, ct = (q >> 6) & 3, l = q & 63;
      int kg = l >> 4, cg = l & 15;
      #pragma unroll
      for (int j = 0; j < 8; ++j) {
        int k = kt * 32 + kg * 8 + j;
        int c = ct * 16 + cg;
        float xv = w1[k * 64 + c];
        unsigned u = __float_as_uint(xv);
        unsigned r = (u + 0x7fffu + ((u >> 16) & 1u)) >> 16;
        float res = xv - __uint_as_float(r << 16);
        pw[q * 8 + j] = (ushort)r;
        pw[8192 + q * 8 + j] = (ushort)(__float_as_uint(res) >> 16);
      }
    }
  }
}

// ---------------- fused SAGE linear pair, 32 rows/block ----------------
__global__ void __launch_bounds__(256) k_sage32(
    int gm,
    const float* __restrict__ aggM, const float* __restrict__ xdM,
    const float* __restrict__ wlM, const float* __restrict__ wrM,
    const float* __restrict__ blM, float* __restrict__ outfM, ushort* __restrict__ outhM,
    const float* __restrict__ aggU, const float* __restrict__ xdU,
    const float* __restrict__ wlU, const float* __restrict__ wrU,
    const float* __restrict__ blU, float* __restrict__ outfU, ushort* __restrict__ outhU,
    int relu) {
  __shared__ float swl[H * H];   // 16 KB
  __shared__ float swr[H * H];   // 16 KB
  __shared__ float sa[32][H];    // 8 KB
  __shared__ float sd[32][H];    // 8 KB
  int tid = threadIdx.x;
  const float *agg, *xd, *wl, *wr, *bl; float* outf; ushort* outh; int r0;
  if ((int)blockIdx.x < gm) {
    agg = aggM; xd = xdM; wl = wlM; wr = wrM; bl = blM; outf = outfM; outh = outhM;
    r0 = blockIdx.x * 32;
  } else {
    agg = aggU; xd = xdU; wl = wlU; wr = wrU; bl = blU; outf = outfU; outh = outhU;
    r0 = (blockIdx.x - gm) * 32;
  }
  #pragma unroll
  for (int it = 0; it < 4; ++it) {
    int idx = tid + it * 256;
    ((float4*)swl)[idx] = ((const float4*)wl)[idx];
    ((float4*)swr)[idx] = ((const float4*)wr)[idx];
  }
  #pragma unroll
  for (int it = 0; it < 2; ++it) {
    int idx = tid + it * 256;       // 512 float4 = 32 rows x 16
    int row = idx >> 4, q = idx & 15;
    *(float4*)&sa[row][q * 4] = ((const float4*)agg)[(size_t)(r0 + row) * 16 + q];
    *(float4*)&sd[row][q * 4] = ((const float4*)xd)[(size_t)(r0 + row) * 16 + q];
  }
  __syncthreads();
  int col = tid & 63, rg = tid >> 6;
  float b = bl[col];
  float acc[8];
  #pragma unroll
  for (int j = 0; j < 8; ++j) acc[j] = b;
  #pragma unroll 2
  for (int k4 = 0; k4 < 16; ++k4) {
    float w0 = swl[(k4 * 4 + 0) * H + col], w1 = swl[(k4 * 4 + 1) * H + col];
    float w2 = swl[(k4 * 4 + 2) * H + col], w3 = swl[(k4 * 4 + 3) * H + col];
    float v0 = swr[(k4 * 4 + 0) * H + col], v1 = swr[(k4 * 4 + 1) * H + col];
    float v2 = swr[(k4 * 4 + 2) * H + col], v3 = swr[(k4 * 4 + 3) * H + col];
    #pragma unroll
    for (int j = 0; j < 8; ++j) {
      int r = rg + j * 4;
      float4 a = *(const float4*)&sa[r][k4 * 4];
      float4 d = *(const float4*)&sd[r][k4 * 4];
      acc[j] += a.x * w0 + a.y * w1 + a.z * w2 + a.w * w3;
      acc[j] += d.x * v0 + d.y * v1 + d.z * v2 + d.w * v3;
    }
  }
  #pragma unroll
  for (int j = 0; j < 8; ++j) {
    int r = rg + j * 4;
    float v = relu ? fmaxf(acc[j], 0.f) : acc[j];
    size_t o = (size_t)(r0 + r) * H + col;
    if (outf) outf[o] = v;
    if (outh) outh[o] = bf16rne(v);
  }
}

// ---------------- MFMA edge decoder: h1 = relu(x@w1+b1); out = h1@w2+b2 ----------------
__global__ void __launch_bounds__(256) k_dec_mfma(
    const ushort* __restrict__ uhi, const ushort* __restrict__ mhi,
    const int* __restrict__ lu, const int* __restrict__ lm,
    const ushort* __restrict__ pw,
    const float* __restrict__ b1, const float* __restrict__ w2,
    const float* __restrict__ b2, float* __restrict__ out) {
  __shared__ ushort sB[2 * 16 * 64 * 8];  // 32 KB packed w1 fragments
  int tid = threadIdx.x;
  #pragma unroll
  for (int it = 0; it < 8; ++it) {
    int idx = tid + it * 256;
    ((float4*)sB)[idx] = ((const float4*)pw)[idx];
  }
  __syncthreads();
  int l = tid & 63, w = tid >> 6;
  int cg = l & 15, kg = l >> 4;
  float w2f[4], b1f[4];
  #pragma unroll
  for (int ct = 0; ct < 4; ++ct) {
    w2f[ct] = w2[ct * 16 + cg];
    b1f[ct] = b1[ct * 16 + cg];
  }
  float b2v = b2[0];
  for (int t = 0; t < 4; ++t) {
    int Lb = blockIdx.x * 256 + w * 64 + t * 16;
    int lab = min(Lb + cg, NL - 1);
    int nu = lu[lab], nm = lm[lab];
    const size_t ub = (size_t)nu * 64 + kg * 8;
    const size_t mb = (size_t)nm * 64 + kg * 8;
    short8v ah[4];
    ah[0] = *(const short8v*)(uhi + ub);
    ah[1] = *(const short8v*)(uhi + ub + 32);
    ah[2] = *(const short8v*)(mhi + mb);
    ah[3] = *(const short8v*)(mhi + mb + 32);
    f32x4 acc[4];
    #pragma unroll
    for (int ct = 0; ct < 4; ++ct) acc[ct] = (f32x4){b1f[ct], b1f[ct], b1f[ct], b1f[ct]};
    #pragma unroll
    for (int kt = 0; kt < 4; ++kt) {
      #pragma unroll
      for (int ct = 0; ct < 4; ++ct) {
        const int f = kt * 4 + ct;
        short8v bh = *(const short8v*)&sB[(size_t)(f * 64 + l) * 8];
        short8v bl_ = *(const short8v*)&sB[(size_t)((16 + f) * 64 + l) * 8];
        acc[ct] = __builtin_amdgcn_mfma_f32_16x16x32_bf16(ah[kt], bh, acc[ct], 0, 0, 0);
        acc[ct] = __builtin_amdgcn_mfma_f32_16x16x32_bf16(ah[kt], bl_, acc[ct], 0, 0, 0);
      }
    }
    float p[4];
    #pragma unroll
    for (int r = 0; r < 4; ++r) {
      p[r] = fmaxf(acc[0][r], 0.f) * w2f[0] + fmaxf(acc[1][r], 0.f) * w2f[1] +
             fmaxf(acc[2][r], 0.f) * w2f[2] + fmaxf(acc[3][r], 0.f) * w2f[3];
    }
    #pragma unroll
    for (int m = 8; m >= 1; m >>= 1) {
      #pragma unroll
      for (int r = 0; r < 4; ++r) p[r] += __shfl_xor(p[r], m, 64);
    }
    if (cg == 0) {
      #pragma unroll
      for (int r = 0; r < 4; ++r) {
        int row = Lb + kg * 4 + r;
        if (row < NL) out[row] = p[r] + b2v;
      }
    }
  }
}

extern "C" void kernel_launch(void* const* d_in, const int* in_sizes, int n_in,
                              void* d_out, int out_size, void* d_ws, size_t ws_size,
                              hipStream_t stream) {
  const float* movie_x  = (const float*)d_in[0];
  const int*   esrc     = (const int*)d_in[1];
  const int*   edst     = (const int*)d_in[2];
  const int*   lu       = (const int*)d_in[3];
  const int*   lm       = (const int*)d_in[4];
  const float* user_emb = (const float*)d_in[5];
  const float* proj_w   = (const float*)d_in[6];
  const float* proj_b   = (const float*)d_in[7];
  const float* dec_w1   = (const float*)d_in[8];
  const float* dec_b1   = (const float*)d_in[9];
  const float* dec_w2   = (const float*)d_in[10];
  const float* dec_b2   = (const float*)d_in[11];
  const float* w1_um_l  = (const float*)d_in[12];
  const float* b1_um_l  = (const float*)d_in[13];
  const float* w1_um_r  = (const float*)d_in[14];
  const float* w1_mu_l  = (const float*)d_in[15];
  const float* b1_mu_l  = (const float*)d_in[16];
  const float* w1_mu_r  = (const float*)d_in[17];
  const float* w2_um_l  = (const float*)d_in[18];
  const float* b2_um_l  = (const float*)d_in[19];
  const float* w2_um_r  = (const float*)d_in[20];
  const float* w2_mu_l  = (const float*)d_in[21];
  const float* b2_mu_l  = (const float*)d_in[22];
  const float* w2_mu_r  = (const float*)d_in[23];

  char* ws = (char*)d_ws;
  size_t off = 0;
  auto alloc = [&](size_t bytes) {
    void* p = ws + off;
    off = (off + bytes + 255) & ~(size_t)255;
    return p;
  };
  float* movie0   = (float*)alloc((size_t)NM * H * 4);
  float* movie1   = (float*)alloc((size_t)NM * H * 4);
  // union: pairs_m+pairs_u (build phase) alias user1+agg regions (written after build)
  float* user1    = (float*)alloc((size_t)NU * H * 4);   // 25.6 MB
  float* agg_m    = (float*)alloc((size_t)NM * H * 4);
  float* agg_u    = (float*)alloc((size_t)NU * H * 4);   // 25.6 MB
  unsigned* pairs_m = (unsigned*)user1;                  // 20.5 MB
  unsigned* pairs_u = pairs_m + (size_t)NBM * CAP_M;     // 19.2 MB, spills into agg region (dead)
  ushort* uembh   = (ushort*)alloc((size_t)NU * H * 2);  // user_emb bf16
  ushort* movie0h = (ushort*)alloc((size_t)NM * H * 2);
  ushort* movie1h = (ushort*)alloc((size_t)NM * H * 2);
  ushort* user1h  = (ushort*)alloc((size_t)NU * H * 2);
  ushort* uhi     = (ushort*)alloc((size_t)NU * H * 2);  // conv2 user output (bf16)
  ushort* mhi     = (ushort*)alloc((size_t)NM * H * 2);  // conv2 movie output (bf16)
  int* st_m      = (int*)alloc((size_t)NM * 4);          // per-node start (gapped CSR)
  int* st_u      = (int*)alloc((size_t)NU * 4);
  int* dg_m      = (int*)alloc((size_t)NM * 4);          // per-node degree
  int* dg_u      = (int*)alloc((size_t)NU * 4);
  int* bcur_m    = (int*)alloc((size_t)NBM * 4);
  int* bcur_u    = (int*)alloc((size_t)NBU * 4);
  int* su_by_m   = (int*)alloc((size_t)NBM * CAP_M * 4);    // 20.5 MB gapped adjacency (int)
  ushort* sm_by_u = (ushort*)alloc((size_t)NBU * CAP_U * 2); // 9.6 MB gapped adjacency (u16)
  ushort* pw     = (ushort*)alloc((size_t)2 * 16 * 64 * 8 * 2);  // 32 KB
  (void)ws_size; (void)in_sizes; (void)n_in; (void)out_size;

  // ---- build gapped per-node CSR: fixed-cap buckets -> per-side bin -> in-bucket sort --
  k_binit2<<<(NBU + 255) / 256, 256, 0, stream>>>(bcur_m, bcur_u);
  int nbPerSide = (NE + B3C - 1) / B3C;   // 196
  k_bin3<<<2 * nbPerSide, 256, 0, stream>>>(esrc, edst, bcur_m, bcur_u,
                                            pairs_m, pairs_u, nbPerSide);
  k_sortb4<<<NBM + NBU, 256, 0, stream>>>(pairs_m, pairs_u, bcur_m, bcur_u,
                                          st_m, dg_m, su_by_m, st_u, dg_u, sm_by_u);

  // fused prep: movie0 = movie_x @ proj_w + proj_b (f32+bf16); user_emb->bf16; packw
  k_prep<<<PB + CB + 1, 256, 0, stream>>>(movie_x, proj_w, proj_b, movie0, movie0h,
                                          user_emb, uembh, dec_w1, pw);

  const int GAM = NM / 4, GAU = NU / 4;        // agg grids
  const int GSM = NM / 32, GSU = NU / 32;      // sage grids

  // conv1
  k_agg2e<<<GAM + GAU, 256, 0, stream>>>(GAM,
      uembh,   st_m, dg_m, su_by_m, agg_m, NM,
      movie0h, st_u, dg_u, sm_by_u, agg_u, NU);
  k_sage32<<<GSM + GSU, 256, 0, stream>>>(GSM,
      agg_m, movie0,   w1_um_l, w1_um_r, b1_um_l, movie1, movie1h,
      agg_u, user_emb, w1_mu_l, w1_mu_r, b1_mu_l, user1,  user1h, 1);

  // conv2 (writes decoder bf16 planes directly)
  k_agg2e<<<GAM + GAU, 256, 0, stream>>>(GAM,
      user1h,  st_m, dg_m, su_by_m, agg_m, NM,
      movie1h, st_u, dg_u, sm_by_u, agg_u, NU);
  k_sage32<<<GSM + GSU, 256, 0, stream>>>(GSM,
      agg_m, movie1, w2_um_l, w2_um_r, b2_um_l, (float*)nullptr, mhi,
      agg_u, user1,  w2_mu_l, w2_mu_r, b2_mu_l, (float*)nullptr, uhi, 0);

  // decoder
  k_dec_mfma<<<(NL + 255) / 256, 256, 0, stream>>>(uhi, mhi, lu, lm, pw,
                                                   dec_b1, dec_w2, dec_b2, (float*)d_out);
}

// Round 13
// 471.479 us; speedup vs baseline: 1.0534x; 1.0534x over previous
//
#include <hip/hip_runtime.h>

static constexpr int NU = 100000;
static constexpr int NM = 20000;
static constexpr int NE = 3200000;
static constexpr int NL = 1000000;
static constexpr int FD = 128;
static constexpr int H  = 64;

// bucket geometry
static constexpr int MBK = 16;                    // movies per bucket
static constexpr int UBK = 64;                    // users per bucket
static constexpr int NBM = NM / MBK;              // 1250
static constexpr int NBU = (NU + UBK - 1) / UBK;  // 1563
// fixed bucket capacities (mean 2560/2048, sigma ~51/45 -> +30/+22 sigma slack)
static constexpr int CAP_M = 4096;
static constexpr int CAP_U = 3072;
static constexpr int B3C = 16384;                 // edges per bin block (per side)

typedef __attribute__((ext_vector_type(8))) short short8v;
typedef __attribute__((ext_vector_type(4))) float f32x4;

__device__ __forceinline__ ushort bf16rne(float x) {
  unsigned u = __float_as_uint(x);
  return (ushort)((u + 0x7fffu + ((u >> 16) & 1u)) >> 16);
}

// ---------------- init bucket cursors to fixed-capacity bases ----------------
__global__ void k_binit2(int* __restrict__ bcur_m, int* __restrict__ bcur_u) {
  int i = blockIdx.x * 256 + threadIdx.x;
  if (i < NBM) bcur_m[i] = i * CAP_M;
  if (i < NBU) bcur_u[i] = i * CAP_U;
}

// ---------------- per-side binned ranked scatter (simple 2-pass) ----------------
// movie-side entry: (d&15)<<17 | s      user-side entry: (s&63)<<15 | d
__global__ void __launch_bounds__(256) k_bin3(
    const int* __restrict__ esrc, const int* __restrict__ edst,
    int* __restrict__ bcur_m, int* __restrict__ bcur_u,
    unsigned* __restrict__ pairs_m, unsigned* __restrict__ pairs_u, int nbPerSide) {
  __shared__ int cnt[NBU];    // 6.1 KB (worst side)
  __shared__ int base[NBU];
  int tid = threadIdx.x;
  bool um = (int)blockIdx.x < nbPerSide;
  int cb = um ? blockIdx.x : blockIdx.x - nbPerSide;
  int nbs = um ? NBM : NBU;
  int sh = um ? 4 : 6;
  int* bcur = um ? bcur_m : bcur_u;
  unsigned* pairs = um ? pairs_m : pairs_u;
  const int* keys = um ? edst : esrc;
  const int* vals = um ? esrc : edst;
  int e0 = cb * B3C, e1 = min(e0 + B3C, NE);
  for (int i = tid; i < nbs; i += 256) cnt[i] = 0;
  __syncthreads();
  // pass 1: count buckets (int4 reads, key array only)
  for (int e = e0 + (tid << 2); e < e1; e += 1024) {
    int4 k = *(const int4*)(keys + e);
    atomicAdd(&cnt[k.x >> sh], 1);
    atomicAdd(&cnt[k.y >> sh], 1);
    atomicAdd(&cnt[k.z >> sh], 1);
    atomicAdd(&cnt[k.w >> sh], 1);
  }
  __syncthreads();
  // reserve global space per touched bucket, reset counters to rank
  for (int i = tid; i < nbs; i += 256) {
    int c = cnt[i];
    if (c > 0) base[i] = atomicAdd(&bcur[i], c);
    cnt[i] = 0;
  }
  __syncthreads();
  // pass 2: ranked write
  int lsh = um ? 17 : 15;
  unsigned lmask = um ? 15u : 63u;
  for (int e = e0 + (tid << 2); e < e1; e += 1024) {
    int4 k = *(const int4*)(keys + e);
    int4 v = *(const int4*)(vals + e);
    int ks[4] = {k.x, k.y, k.z, k.w};
    int vs[4] = {v.x, v.y, v.z, v.w};
    #pragma unroll
    for (int j = 0; j < 4; ++j) {
      int b = ks[j] >> sh;
      int r = atomicAdd(&cnt[b], 1);
      pairs[base[b] + r] = (((unsigned)ks[j] & lmask) << lsh) | (unsigned)vs[j];
    }
  }
}

// ---------------- per-bucket counting sort -> gapped per-node CSR ----------------
__global__ void __launch_bounds__(256) k_sortb4(
    const unsigned* __restrict__ pairs_m, const unsigned* __restrict__ pairs_u,
    const int* __restrict__ bcur_m, const int* __restrict__ bcur_u,
    int* __restrict__ st_m, int* __restrict__ dg_m, int* __restrict__ out_m,
    int* __restrict__ st_u, int* __restrict__ dg_u, ushort* __restrict__ out_u) {
  __shared__ int cnt[64];
  __shared__ int cbase[64];
  const unsigned* pairs; const int* bcur; int* start; int* deg;
  int b, npb, shift, cap, n; unsigned mask;
  bool um = (int)blockIdx.x < NBM;
  if (um) {
    pairs = pairs_m; bcur = bcur_m; start = st_m; deg = dg_m;
    b = blockIdx.x; npb = MBK; shift = 17; mask = 0x1FFFFu; cap = CAP_M; n = NM;
  } else {
    pairs = pairs_u; bcur = bcur_u; start = st_u; deg = dg_u;
    b = blockIdx.x - NBM; npb = UBK; shift = 15; mask = 0x7FFFu; cap = CAP_U; n = NU;
  }
  int tid = threadIdx.x;
  if (tid < 64) cnt[tid] = 0;
  __syncthreads();
  int e0 = b * cap, e1 = bcur[b];
  for (int e = e0 + tid; e < e1; e += 256) atomicAdd(&cnt[pairs[e] >> shift], 1);
  __syncthreads();
  if (tid < 64) {
    int c = cnt[tid];
    int v = c;
    #pragma unroll
    for (int off = 1; off < 64; off <<= 1) {
      int t = __shfl_up(v, off, 64);
      if (tid >= off) v += t;
    }
    int basee = e0 + v - c;
    cbase[tid] = basee;
    int node = b * npb + tid;
    if (tid < npb && node < n) { start[node] = basee; deg[node] = c; }
    cnt[tid] = 0;
  }
  __syncthreads();
  for (int e = e0 + tid; e < e1; e += 256) {
    unsigned v = pairs[e];
    int loc = (int)(v >> shift);
    int r = atomicAdd(&cnt[loc], 1);
    if (um) out_m[cbase[loc] + r] = (int)(v & mask);
    else    out_u[cbase[loc] + r] = (ushort)(v & mask);
  }
}

// ---------------- aggregation node helpers (round-11 proven: 24 VGPR, 78% occ) -----
#define ACC4(vv)                                                           \
  a0 += __uint_as_float((vv).x << 16); a1 += __uint_as_float((vv).x & 0xffff0000u); \
  a2 += __uint_as_float((vv).y << 16); a3 += __uint_as_float((vv).y & 0xffff0000u); \
  a4 += __uint_as_float((vv).z << 16); a5 += __uint_as_float((vv).z & 0xffff0000u); \
  a6 += __uint_as_float((vv).w << 16); a7 += __uint_as_float((vv).w & 0xffff0000u);

// movie side: int idx, 8 feats x 8 nbrs per wave iter (deg mean 160)
__device__ __forceinline__ void agg_node_w8(const ushort* __restrict__ feat,
                                            const int* __restrict__ idxs,
                                            int s, int degn, float* __restrict__ out,
                                            int d, int lane) {
  int f8 = lane & 7, p = lane >> 3;
  int e = s + degn;
  float a0 = 0.f, a1 = 0.f, a2 = 0.f, a3 = 0.f, a4 = 0.f, a5 = 0.f, a6 = 0.f, a7 = 0.f;
  int i = s;
  for (; i + 32 <= e; i += 32) {
    int s0 = idxs[i + 0 + p];
    int s1 = idxs[i + 8 + p];
    int s2 = idxs[i + 16 + p];
    int s3 = idxs[i + 24 + p];
    uint4 v0 = *(const uint4*)(feat + ((size_t)s0 << 6) + (f8 << 3));
    uint4 v1 = *(const uint4*)(feat + ((size_t)s1 << 6) + (f8 << 3));
    uint4 v2 = *(const uint4*)(feat + ((size_t)s2 << 6) + (f8 << 3));
    uint4 v3 = *(const uint4*)(feat + ((size_t)s3 << 6) + (f8 << 3));
    ACC4(v0) ACC4(v1) ACC4(v2) ACC4(v3)
  }
  for (; i < e; i += 8) {
    int ii = i + p;
    bool ok = ii < e;
    int sj = idxs[ok ? ii : i];
    uint4 v = *(const uint4*)(feat + ((size_t)sj << 6) + (f8 << 3));
    if (!ok) { v.x = 0u; v.y = 0u; v.z = 0u; v.w = 0u; }
    ACC4(v)
  }
  #pragma unroll
  for (int m = 8; m < 64; m <<= 1) {
    a0 += __shfl_xor(a0, m, 64); a1 += __shfl_xor(a1, m, 64);
    a2 += __shfl_xor(a2, m, 64); a3 += __shfl_xor(a3, m, 64);
    a4 += __shfl_xor(a4, m, 64); a5 += __shfl_xor(a5, m, 64);
    a6 += __shfl_xor(a6, m, 64); a7 += __shfl_xor(a7, m, 64);
  }
  if (p == 0) {
    float inv = 1.f / fmaxf((float)degn, 1.f);
    float4 o0 = make_float4(a0 * inv, a1 * inv, a2 * inv, a3 * inv);
    float4 o1 = make_float4(a4 * inv, a5 * inv, a6 * inv, a7 * inv);
    *(float4*)&out[((size_t)d << 6) + (f8 << 3)] = o0;
    *(float4*)&out[((size_t)d << 6) + (f8 << 3) + 4] = o1;
  }
}

// user side: ushort idx, 4 feats x 4 nbrs per wave-load (deg mean 32)
__device__ __forceinline__ void agg_node_w4(const ushort* __restrict__ feat,
                                            const ushort* __restrict__ idxs,
                                            int s, int degn, float* __restrict__ out,
                                            int d, int lane) {
  int f4 = lane & 15, p = lane >> 4;
  int e = s + degn;
  float a0 = 0.f, a1 = 0.f, a2 = 0.f, a3 = 0.f;
  int i = s;
  for (; i + 16 <= e; i += 16) {
    int s0 = idxs[i + 0 + p];
    int s1 = idxs[i + 4 + p];
    int s2 = idxs[i + 8 + p];
    int s3 = idxs[i + 12 + p];
    uint2 v0 = *(const uint2*)(feat + ((size_t)s0 << 6) + (f4 << 2));
    uint2 v1 = *(const uint2*)(feat + ((size_t)s1 << 6) + (f4 << 2));
    uint2 v2 = *(const uint2*)(feat + ((size_t)s2 << 6) + (f4 << 2));
    uint2 v3 = *(const uint2*)(feat + ((size_t)s3 << 6) + (f4 << 2));
    a0 += __uint_as_float(v0.x << 16); a1 += __uint_as_float(v0.x & 0xffff0000u);
    a2 += __uint_as_float(v0.y << 16); a3 += __uint_as_float(v0.y & 0xffff0000u);
    a0 += __uint_as_float(v1.x << 16); a1 += __uint_as_float(v1.x & 0xffff0000u);
    a2 += __uint_as_float(v1.y << 16); a3 += __uint_as_float(v1.y & 0xffff0000u);
    a0 += __uint_as_float(v2.x << 16); a1 += __uint_as_float(v2.x & 0xffff0000u);
    a2 += __uint_as_float(v2.y << 16); a3 += __uint_as_float(v2.y & 0xffff0000u);
    a0 += __uint_as_float(v3.x << 16); a1 += __uint_as_float(v3.x & 0xffff0000u);
    a2 += __uint_as_float(v3.y << 16); a3 += __uint_as_float(v3.y & 0xffff0000u);
  }
  for (; i < e; i += 4) {
    int ii = i + p;
    bool ok = ii < e;
    int sj = idxs[ok ? ii : i];
    uint2 v = *(const uint2*)(feat + ((size_t)sj << 6) + (f4 << 2));
    if (!ok) { v.x = 0u; v.y = 0u; }
    a0 += __uint_as_float(v.x << 16); a1 += __uint_as_float(v.x & 0xffff0000u);
    a2 += __uint_as_float(v.y << 16); a3 += __uint_as_float(v.y & 0xffff0000u);
  }
  a0 += __shfl_xor(a0, 16, 64); a1 += __shfl_xor(a1, 16, 64);
  a2 += __shfl_xor(a2, 16, 64); a3 += __shfl_xor(a3, 16, 64);
  a0 += __shfl_xor(a0, 32, 64); a1 += __shfl_xor(a1, 32, 64);
  a2 += __shfl_xor(a2, 32, 64); a3 += __shfl_xor(a3, 32, 64);
  if (p == 0) {
    float inv = 1.f / fmaxf((float)degn, 1.f);
    float4 o = make_float4(a0 * inv, a1 * inv, a2 * inv, a3 * inv);
    *(float4*)&out[((size_t)d << 6) + (f4 << 2)] = o;
  }
}

// ---------------- fused mean aggregation (both directions in one grid) ----------------
__global__ void __launch_bounds__(256) k_agg2d(
    int gm,
    const ushort* __restrict__ fM, const int* __restrict__ stM, const int* __restrict__ dgM,
    const int* __restrict__ idxM, float* __restrict__ outM, int nM,
    const ushort* __restrict__ fU, const int* __restrict__ stU, const int* __restrict__ dgU,
    const ushort* __restrict__ idxU, float* __restrict__ outU, int nU) {
  int lane = threadIdx.x & 63;
  if ((int)blockIdx.x < gm) {
    int d = blockIdx.x * 4 + (threadIdx.x >> 6);
    if (d >= nM) return;
    agg_node_w8(fM, idxM, stM[d], dgM[d], outM, d, lane);
  } else {
    int d = (blockIdx.x - gm) * 4 + (threadIdx.x >> 6);
    if (d >= nU) return;
    agg_node_w4(fU, idxU, stU[d], dgU[d], outU, d, lane);
  }
}

// ---------------- fused prep: movie proj (16 rows/blk) + user cvt + packw ----------
static constexpr int PB = NM / 16;                // 1250 proj blocks
static constexpr int CB = (NU * H / 4) / 256;     // 6250 cvt blocks (exact)
__global__ void __launch_bounds__(256) k_prep(
    const float* __restrict__ x, const float* __restrict__ w, const float* __restrict__ b,
    float* __restrict__ out, ushort* __restrict__ outh,
    const float* __restrict__ uemb, ushort* __restrict__ uembh,
    const float* __restrict__ w1, ushort* __restrict__ pw) {
  __shared__ float sw[FD * H];    // 32 KB
  __shared__ float sx[16][FD];    // 8 KB
  int tid = threadIdx.x;
  int blk = blockIdx.x;
  if (blk < PB) {
    int r0 = blk * 16;
    #pragma unroll
    for (int it = 0; it < 8; ++it) {
      int idx = tid + it * 256;
      ((float4*)sw)[idx] = ((const float4*)w)[idx];
    }
    #pragma unroll
    for (int it = 0; it < 2; ++it) {
      int idx = tid + it * 256;
      int row = idx >> 5, q = idx & 31;
      *(float4*)&sx[row][q * 4] = ((const float4*)x)[(size_t)(r0 + row) * 32 + q];
    }
    __syncthreads();
    int col = tid & 63, rg = tid >> 6;
    float bb = b[col];
    float acc[4];
    #pragma unroll
    for (int j = 0; j < 4; ++j) acc[j] = bb;
    #pragma unroll 4
    for (int k4 = 0; k4 < 32; ++k4) {
      float w0 = sw[(k4 * 4 + 0) * H + col], w1_ = sw[(k4 * 4 + 1) * H + col];
      float w2 = sw[(k4 * 4 + 2) * H + col], w3 = sw[(k4 * 4 + 3) * H + col];
      #pragma unroll
      for (int j = 0; j < 4; ++j) {
        float4 a = *(const float4*)&sx[rg + j * 4][k4 * 4];
        acc[j] += a.x * w0 + a.y * w1_ + a.z * w2 + a.w * w3;
      }
    }
    #pragma unroll
    for (int j = 0; j < 4; ++j) {
      size_t o = (size_t)(r0 + rg + j * 4) * H + col;
      out[o] = acc[j];
      outh[o] = bf16rne(acc[j]);
    }
  } else if (blk < PB + CB) {
    int i = (blk - PB) * 256 + tid;
    float4 v = ((const float4*)uemb)[i];
    ushort4 o;
    o.x = bf16rne(v.x); o.y = bf16rne(v.y); o.z = bf16rne(v.z); o.w = bf16rne(v.w);
    ((ushort4*)uembh)[i] = o;
  } else {
    for (int it = 0; it < 4; ++it) {
      int q = tid + it * 256;
      int kt = q >> 8, ct = (q >> 6) & 3, l = q & 63;
      int kg = l >> 4, cg = l & 15;
      #pragma unroll
      for (int j = 0; j < 8; ++j) {
        int k = kt * 32 + kg * 8 + j;
        int c = ct * 16 + cg;
        float xv = w1[k * 64 + c];
        unsigned u = __float_as_uint(xv);
        unsigned r = (u + 0x7fffu + ((u >> 16) & 1u)) >> 16;
        float res = xv - __uint_as_float(r << 16);
        pw[q * 8 + j] = (ushort)r;
        pw[8192 + q * 8 + j] = (ushort)(__float_as_uint(res) >> 16);
      }
    }
  }
}

// ---------------- fused SAGE linear pair, 32 rows/block ----------------
__global__ void __launch_bounds__(256) k_sage32(
    int gm,
    const float* __restrict__ aggM, const float* __restrict__ xdM,
    const float* __restrict__ wlM, const float* __restrict__ wrM,
    const float* __restrict__ blM, float* __restrict__ outfM, ushort* __restrict__ outhM,
    const float* __restrict__ aggU, const float* __restrict__ xdU,
    const float* __restrict__ wlU, const float* __restrict__ wrU,
    const float* __restrict__ blU, float* __restrict__ outfU, ushort* __restrict__ outhU,
    int relu) {
  __shared__ float swl[H * H];   // 16 KB
  __shared__ float swr[H * H];   // 16 KB
  __shared__ float sa[32][H];    // 8 KB
  __shared__ float sd[32][H];    // 8 KB
  int tid = threadIdx.x;
  const float *agg, *xd, *wl, *wr, *bl; float* outf; ushort* outh; int r0;
  if ((int)blockIdx.x < gm) {
    agg = aggM; xd = xdM; wl = wlM; wr = wrM; bl = blM; outf = outfM; outh = outhM;
    r0 = blockIdx.x * 32;
  } else {
    agg = aggU; xd = xdU; wl = wlU; wr = wrU; bl = blU; outf = outfU; outh = outhU;
    r0 = (blockIdx.x - gm) * 32;
  }
  #pragma unroll
  for (int it = 0; it < 4; ++it) {
    int idx = tid + it * 256;
    ((float4*)swl)[idx] = ((const float4*)wl)[idx];
    ((float4*)swr)[idx] = ((const float4*)wr)[idx];
  }
  #pragma unroll
  for (int it = 0; it < 2; ++it) {
    int idx = tid + it * 256;       // 512 float4 = 32 rows x 16
    int row = idx >> 4, q = idx & 15;
    *(float4*)&sa[row][q * 4] = ((const float4*)agg)[(size_t)(r0 + row) * 16 + q];
    *(float4*)&sd[row][q * 4] = ((const float4*)xd)[(size_t)(r0 + row) * 16 + q];
  }
  __syncthreads();
  int col = tid & 63, rg = tid >> 6;
  float b = bl[col];
  float acc[8];
  #pragma unroll
  for (int j = 0; j < 8; ++j) acc[j] = b;
  #pragma unroll 2
  for (int k4 = 0; k4 < 16; ++k4) {
    float w0 = swl[(k4 * 4 + 0) * H + col], w1 = swl[(k4 * 4 + 1) * H + col];
    float w2 = swl[(k4 * 4 + 2) * H + col], w3 = swl[(k4 * 4 + 3) * H + col];
    float v0 = swr[(k4 * 4 + 0) * H + col], v1 = swr[(k4 * 4 + 1) * H + col];
    float v2 = swr[(k4 * 4 + 2) * H + col], v3 = swr[(k4 * 4 + 3) * H + col];
    #pragma unroll
    for (int j = 0; j < 8; ++j) {
      int r = rg + j * 4;
      float4 a = *(const float4*)&sa[r][k4 * 4];
      float4 d = *(const float4*)&sd[r][k4 * 4];
      acc[j] += a.x * w0 + a.y * w1 + a.z * w2 + a.w * w3;
      acc[j] += d.x * v0 + d.y * v1 + d.z * v2 + d.w * v3;
    }
  }
  #pragma unroll
  for (int j = 0; j < 8; ++j) {
    int r = rg + j * 4;
    float v = relu ? fmaxf(acc[j], 0.f) : acc[j];
    size_t o = (size_t)(r0 + r) * H + col;
    if (outf) outf[o] = v;
    if (outh) outh[o] = bf16rne(v);
  }
}

// ---------------- MFMA edge decoder: h1 = relu(x@w1+b1); out = h1@w2+b2 ----------------
__global__ void __launch_bounds__(256) k_dec_mfma(
    const ushort* __restrict__ uhi, const ushort* __restrict__ mhi,
    const int* __restrict__ lu, const int* __restrict__ lm,
    const ushort* __restrict__ pw,
    const float* __restrict__ b1, const float* __restrict__ w2,
    const float* __restrict__ b2, float* __restrict__ out) {
  __shared__ ushort sB[2 * 16 * 64 * 8];  // 32 KB packed w1 fragments
  int tid = threadIdx.x;
  #pragma unroll
  for (int it = 0; it < 8; ++it) {
    int idx = tid + it * 256;
    ((float4*)sB)[idx] = ((const float4*)pw)[idx];
  }
  __syncthreads();
  int l = tid & 63, w = tid >> 6;
  int cg = l & 15, kg = l >> 4;
  float w2f[4], b1f[4];
  #pragma unroll
  for (int ct = 0; ct < 4; ++ct) {
    w2f[ct] = w2[ct * 16 + cg];
    b1f[ct] = b1[ct * 16 + cg];
  }
  float b2v = b2[0];
  for (int t = 0; t < 4; ++t) {
    int Lb = blockIdx.x * 256 + w * 64 + t * 16;
    int lab = min(Lb + cg, NL - 1);
    int nu = lu[lab], nm = lm[lab];
    const size_t ub = (size_t)nu * 64 + kg * 8;
    const size_t mb = (size_t)nm * 64 + kg * 8;
    short8v ah[4];
    ah[0] = *(const short8v*)(uhi + ub);
    ah[1] = *(const short8v*)(uhi + ub + 32);
    ah[2] = *(const short8v*)(mhi + mb);
    ah[3] = *(const short8v*)(mhi + mb + 32);
    f32x4 acc[4];
    #pragma unroll
    for (int ct = 0; ct < 4; ++ct) acc[ct] = (f32x4){b1f[ct], b1f[ct], b1f[ct], b1f[ct]};
    #pragma unroll
    for (int kt = 0; kt < 4; ++kt) {
      #pragma unroll
      for (int ct = 0; ct < 4; ++ct) {
        const int f = kt * 4 + ct;
        short8v bh = *(const short8v*)&sB[(size_t)(f * 64 + l) * 8];
        short8v bl_ = *(const short8v*)&sB[(size_t)((16 + f) * 64 + l) * 8];
        acc[ct] = __builtin_amdgcn_mfma_f32_16x16x32_bf16(ah[kt], bh, acc[ct], 0, 0, 0);
        acc[ct] = __builtin_amdgcn_mfma_f32_16x16x32_bf16(ah[kt], bl_, acc[ct], 0, 0, 0);
      }
    }
    float p[4];
    #pragma unroll
    for (int r = 0; r < 4; ++r) {
      p[r] = fmaxf(acc[0][r], 0.f) * w2f[0] + fmaxf(acc[1][r], 0.f) * w2f[1] +
             fmaxf(acc[2][r], 0.f) * w2f[2] + fmaxf(acc[3][r], 0.f) * w2f[3];
    }
    #pragma unroll
    for (int m = 8; m >= 1; m >>= 1) {
      #pragma unroll
      for (int r = 0; r < 4; ++r) p[r] += __shfl_xor(p[r], m, 64);
    }
    if (cg == 0) {
      #pragma unroll
      for (int r = 0; r < 4; ++r) {
        int row = Lb + kg * 4 + r;
        if (row < NL) out[row] = p[r] + b2v;
      }
    }
  }
}

extern "C" void kernel_launch(void* const* d_in, const int* in_sizes, int n_in,
                              void* d_out, int out_size, void* d_ws, size_t ws_size,
                              hipStream_t stream) {
  const float* movie_x  = (const float*)d_in[0];
  const int*   esrc     = (const int*)d_in[1];
  const int*   edst     = (const int*)d_in[2];
  const int*   lu       = (const int*)d_in[3];
  const int*   lm       = (const int*)d_in[4];
  const float* user_emb = (const float*)d_in[5];
  const float* proj_w   = (const float*)d_in[6];
  const float* proj_b   = (const float*)d_in[7];
  const float* dec_w1   = (const float*)d_in[8];
  const float* dec_b1   = (const float*)d_in[9];
  const float* dec_w2   = (const float*)d_in[10];
  const float* dec_b2   = (const float*)d_in[11];
  const float* w1_um_l  = (const float*)d_in[12];
  const float* b1_um_l  = (const float*)d_in[13];
  const float* w1_um_r  = (const float*)d_in[14];
  const float* w1_mu_l  = (const float*)d_in[15];
  const float* b1_mu_l  = (const float*)d_in[16];
  const float* w1_mu_r  = (const float*)d_in[17];
  const float* w2_um_l  = (const float*)d_in[18];
  const float* b2_um_l  = (const float*)d_in[19];
  const float* w2_um_r  = (const float*)d_in[20];
  const float* w2_mu_l  = (const float*)d_in[21];
  const float* b2_mu_l  = (const float*)d_in[22];
  const float* w2_mu_r  = (const float*)d_in[23];

  char* ws = (char*)d_ws;
  size_t off = 0;
  auto alloc = [&](size_t bytes) {
    void* p = ws + off;
    off = (off + bytes + 255) & ~(size_t)255;
    return p;
  };
  float* movie0   = (float*)alloc((size_t)NM * H * 4);
  float* movie1   = (float*)alloc((size_t)NM * H * 4);
  // union: pairs_m+pairs_u (build phase) alias user1+agg regions (written after build)
  float* user1    = (float*)alloc((size_t)NU * H * 4);   // 25.6 MB
  float* agg_m    = (float*)alloc((size_t)NM * H * 4);
  float* agg_u    = (float*)alloc((size_t)NU * H * 4);   // 25.6 MB
  unsigned* pairs_m = (unsigned*)user1;                  // 20.5 MB
  unsigned* pairs_u = pairs_m + (size_t)NBM * CAP_M;     // 19.2 MB, spills into agg region (dead)
  ushort* uembh   = (ushort*)alloc((size_t)NU * H * 2);  // user_emb bf16
  ushort* movie0h = (ushort*)alloc((size_t)NM * H * 2);
  ushort* movie1h = (ushort*)alloc((size_t)NM * H * 2);
  ushort* user1h  = (ushort*)alloc((size_t)NU * H * 2);
  ushort* uhi     = (ushort*)alloc((size_t)NU * H * 2);  // conv2 user output (bf16)
  ushort* mhi     = (ushort*)alloc((size_t)NM * H * 2);  // conv2 movie output (bf16)
  int* st_m      = (int*)alloc((size_t)NM * 4);          // per-node start (gapped CSR)
  int* st_u      = (int*)alloc((size_t)NU * 4);
  int* dg_m      = (int*)alloc((size_t)NM * 4);          // per-node degree
  int* dg_u      = (int*)alloc((size_t)NU * 4);
  int* bcur_m    = (int*)alloc((size_t)NBM * 4);
  int* bcur_u    = (int*)alloc((size_t)NBU * 4);
  int* su_by_m   = (int*)alloc((size_t)NBM * CAP_M * 4);    // 20.5 MB gapped adjacency (int)
  ushort* sm_by_u = (ushort*)alloc((size_t)NBU * CAP_U * 2); // 9.6 MB gapped adjacency (u16)
  ushort* pw     = (ushort*)alloc((size_t)2 * 16 * 64 * 8 * 2);  // 32 KB
  (void)ws_size; (void)in_sizes; (void)n_in; (void)out_size;

  // ---- build gapped per-node CSR: fixed-cap buckets -> per-side bin -> in-bucket sort --
  k_binit2<<<(NBU + 255) / 256, 256, 0, stream>>>(bcur_m, bcur_u);
  int nbPerSide = (NE + B3C - 1) / B3C;   // 196
  k_bin3<<<2 * nbPerSide, 256, 0, stream>>>(esrc, edst, bcur_m, bcur_u,
                                            pairs_m, pairs_u, nbPerSide);
  k_sortb4<<<NBM + NBU, 256, 0, stream>>>(pairs_m, pairs_u, bcur_m, bcur_u,
                                          st_m, dg_m, su_by_m, st_u, dg_u, sm_by_u);

  // fused prep: movie0 = movie_x @ proj_w + proj_b (f32+bf16); user_emb->bf16; packw
  k_prep<<<PB + CB + 1, 256, 0, stream>>>(movie_x, proj_w, proj_b, movie0, movie0h,
                                          user_emb, uembh, dec_w1, pw);

  const int GAM = NM / 4, GAU = NU / 4;        // agg grids
  const int GSM = NM / 32, GSU = NU / 32;      // sage grids

  // conv1
  k_agg2d<<<GAM + GAU, 256, 0, stream>>>(GAM,
      uembh,   st_m, dg_m, su_by_m, agg_m, NM,
      movie0h, st_u, dg_u, sm_by_u, agg_u, NU);
  k_sage32<<<GSM + GSU, 256, 0, stream>>>(GSM,
      agg_m, movie0,   w1_um_l, w1_um_r, b1_um_l, movie1, movie1h,
      agg_u, user_emb, w1_mu_l, w1_mu_r, b1_mu_l, user1,  user1h, 1);

  // conv2 (writes decoder bf16 planes directly)
  k_agg2d<<<GAM + GAU, 256, 0, stream>>>(GAM,
      user1h,  st_m, dg_m, su_by_m, agg_m, NM,
      movie1h, st_u, dg_u, sm_by_u, agg_u, NU);
  k_sage32<<<GSM + GSU, 256, 0, stream>>>(GSM,
      agg_m, movie1, w2_um_l, w2_um_r, b2_um_l, (float*)nullptr, mhi,
      agg_u, user1,  w2_mu_l, w2_mu_r, b2_mu_l, (float*)nullptr, uhi, 0);

  // decoder
  k_dec_mfma<<<(NL + 255) / 256, 256, 0, stream>>>(uhi, mhi, lu, lm, pw,
                                                   dec_b1, dec_w2, dec_b2, (float*)d_out);
}

// Round 14
// 458.588 us; speedup vs baseline: 1.0830x; 1.0281x over previous
//
#include <hip/hip_runtime.h>

static constexpr int NU = 100000;
static constexpr int NM = 20000;
static constexpr int NE = 3200000;
static constexpr int NL = 1000000;
static constexpr int FD = 128;
static constexpr int H  = 64;

// bucket geometry
static constexpr int MBK = 16;                    // movies per bucket
static constexpr int UBK = 64;                    // users per bucket
static constexpr int NBM = NM / MBK;              // 1250
static constexpr int NBU = (NU + UBK - 1) / UBK;  // 1563
// fixed bucket capacities (mean 2560/2048, sigma ~51/45 -> +30/+22 sigma slack)
static constexpr int CAP_M = 4096;
static constexpr int CAP_U = 3072;
static constexpr int B3C = 16384;                 // edges per bin block (per side)

typedef __attribute__((ext_vector_type(8))) short short8v;
typedef __attribute__((ext_vector_type(4))) float f32x4;

__device__ __forceinline__ ushort bf16rne(float x) {
  unsigned u = __float_as_uint(x);
  return (ushort)((u + 0x7fffu + ((u >> 16) & 1u)) >> 16);
}

// ---------------- init bucket cursors to fixed-capacity bases ----------------
__global__ void k_binit2(int* __restrict__ bcur_m, int* __restrict__ bcur_u) {
  int i = blockIdx.x * 256 + threadIdx.x;
  if (i < NBM) bcur_m[i] = i * CAP_M;
  if (i < NBU) bcur_u[i] = i * CAP_U;
}

// ---------------- per-side binned ranked scatter (simple 2-pass) ----------------
// movie-side entry: (d&15)<<17 | s      user-side entry: (s&63)<<15 | d
__global__ void __launch_bounds__(256) k_bin3(
    const int* __restrict__ esrc, const int* __restrict__ edst,
    int* __restrict__ bcur_m, int* __restrict__ bcur_u,
    unsigned* __restrict__ pairs_m, unsigned* __restrict__ pairs_u, int nbPerSide) {
  __shared__ int cnt[NBU];    // 6.1 KB (worst side)
  __shared__ int base[NBU];
  int tid = threadIdx.x;
  bool um = (int)blockIdx.x < nbPerSide;
  int cb = um ? blockIdx.x : blockIdx.x - nbPerSide;
  int nbs = um ? NBM : NBU;
  int sh = um ? 4 : 6;
  int* bcur = um ? bcur_m : bcur_u;
  unsigned* pairs = um ? pairs_m : pairs_u;
  const int* keys = um ? edst : esrc;
  const int* vals = um ? esrc : edst;
  int e0 = cb * B3C, e1 = min(e0 + B3C, NE);
  for (int i = tid; i < nbs; i += 256) cnt[i] = 0;
  __syncthreads();
  // pass 1: count buckets (int4 reads, key array only)
  for (int e = e0 + (tid << 2); e < e1; e += 1024) {
    int4 k = *(const int4*)(keys + e);
    atomicAdd(&cnt[k.x >> sh], 1);
    atomicAdd(&cnt[k.y >> sh], 1);
    atomicAdd(&cnt[k.z >> sh], 1);
    atomicAdd(&cnt[k.w >> sh], 1);
  }
  __syncthreads();
  // reserve global space per touched bucket, reset counters to rank
  for (int i = tid; i < nbs; i += 256) {
    int c = cnt[i];
    if (c > 0) base[i] = atomicAdd(&bcur[i], c);
    cnt[i] = 0;
  }
  __syncthreads();
  // pass 2: ranked write
  int lsh = um ? 17 : 15;
  unsigned lmask = um ? 15u : 63u;
  for (int e = e0 + (tid << 2); e < e1; e += 1024) {
    int4 k = *(const int4*)(keys + e);
    int4 v = *(const int4*)(vals + e);
    int ks[4] = {k.x, k.y, k.z, k.w};
    int vs[4] = {v.x, v.y, v.z, v.w};
    #pragma unroll
    for (int j = 0; j < 4; ++j) {
      int b = ks[j] >> sh;
      int r = atomicAdd(&cnt[b], 1);
      pairs[base[b] + r] = (((unsigned)ks[j] & lmask) << lsh) | (unsigned)vs[j];
    }
  }
}

// ---------------- per-bucket counting sort -> gapped per-node CSR ----------------
__global__ void __launch_bounds__(256) k_sortb4(
    const unsigned* __restrict__ pairs_m, const unsigned* __restrict__ pairs_u,
    const int* __restrict__ bcur_m, const int* __restrict__ bcur_u,
    int* __restrict__ st_m, int* __restrict__ dg_m, int* __restrict__ out_m,
    int* __restrict__ st_u, int* __restrict__ dg_u, ushort* __restrict__ out_u) {
  __shared__ int cnt[64];
  __shared__ int cbase[64];
  const unsigned* pairs; const int* bcur; int* start; int* deg;
  int b, npb, shift, cap, n; unsigned mask;
  bool um = (int)blockIdx.x < NBM;
  if (um) {
    pairs = pairs_m; bcur = bcur_m; start = st_m; deg = dg_m;
    b = blockIdx.x; npb = MBK; shift = 17; mask = 0x1FFFFu; cap = CAP_M; n = NM;
  } else {
    pairs = pairs_u; bcur = bcur_u; start = st_u; deg = dg_u;
    b = blockIdx.x - NBM; npb = UBK; shift = 15; mask = 0x7FFFu; cap = CAP_U; n = NU;
  }
  int tid = threadIdx.x;
  if (tid < 64) cnt[tid] = 0;
  __syncthreads();
  int e0 = b * cap, e1 = bcur[b];
  for (int e = e0 + tid; e < e1; e += 256) atomicAdd(&cnt[pairs[e] >> shift], 1);
  __syncthreads();
  if (tid < 64) {
    int c = cnt[tid];
    int v = c;
    #pragma unroll
    for (int off = 1; off < 64; off <<= 1) {
      int t = __shfl_up(v, off, 64);
      if (tid >= off) v += t;
    }
    int basee = e0 + v - c;
    cbase[tid] = basee;
    int node = b * npb + tid;
    if (tid < npb && node < n) { start[node] = basee; deg[node] = c; }
    cnt[tid] = 0;
  }
  __syncthreads();
  for (int e = e0 + tid; e < e1; e += 256) {
    unsigned v = pairs[e];
    int loc = (int)(v >> shift);
    int r = atomicAdd(&cnt[loc], 1);
    if (um) out_m[cbase[loc] + r] = (int)(v & mask);
    else    out_u[cbase[loc] + r] = (ushort)(v & mask);
  }
}

// ---------------- aggregation node helpers (round-11 proven: 24 VGPR, 78% occ) -----
#define ACC4(vv)                                                           \
  a0 += __uint_as_float((vv).x << 16); a1 += __uint_as_float((vv).x & 0xffff0000u); \
  a2 += __uint_as_float((vv).y << 16); a3 += __uint_as_float((vv).y & 0xffff0000u); \
  a4 += __uint_as_float((vv).z << 16); a5 += __uint_as_float((vv).z & 0xffff0000u); \
  a6 += __uint_as_float((vv).w << 16); a7 += __uint_as_float((vv).w & 0xffff0000u);

// movie side: int idx, 8 feats x 8 nbrs per wave iter (deg mean 160)
__device__ __forceinline__ void agg_node_w8(const ushort* __restrict__ feat,
                                            const int* __restrict__ idxs,
                                            int s, int degn, float* __restrict__ out,
                                            int d, int lane) {
  int f8 = lane & 7, p = lane >> 3;
  int e = s + degn;
  float a0 = 0.f, a1 = 0.f, a2 = 0.f, a3 = 0.f, a4 = 0.f, a5 = 0.f, a6 = 0.f, a7 = 0.f;
  int i = s;
  for (; i + 32 <= e; i += 32) {
    int s0 = idxs[i + 0 + p];
    int s1 = idxs[i + 8 + p];
    int s2 = idxs[i + 16 + p];
    int s3 = idxs[i + 24 + p];
    uint4 v0 = *(const uint4*)(feat + ((size_t)s0 << 6) + (f8 << 3));
    uint4 v1 = *(const uint4*)(feat + ((size_t)s1 << 6) + (f8 << 3));
    uint4 v2 = *(const uint4*)(feat + ((size_t)s2 << 6) + (f8 << 3));
    uint4 v3 = *(const uint4*)(feat + ((size_t)s3 << 6) + (f8 << 3));
    ACC4(v0) ACC4(v1) ACC4(v2) ACC4(v3)
  }
  for (; i < e; i += 8) {
    int ii = i + p;
    bool ok = ii < e;
    int sj = idxs[ok ? ii : i];
    uint4 v = *(const uint4*)(feat + ((size_t)sj << 6) + (f8 << 3));
    if (!ok) { v.x = 0u; v.y = 0u; v.z = 0u; v.w = 0u; }
    ACC4(v)
  }
  #pragma unroll
  for (int m = 8; m < 64; m <<= 1) {
    a0 += __shfl_xor(a0, m, 64); a1 += __shfl_xor(a1, m, 64);
    a2 += __shfl_xor(a2, m, 64); a3 += __shfl_xor(a3, m, 64);
    a4 += __shfl_xor(a4, m, 64); a5 += __shfl_xor(a5, m, 64);
    a6 += __shfl_xor(a6, m, 64); a7 += __shfl_xor(a7, m, 64);
  }
  if (p == 0) {
    float inv = 1.f / fmaxf((float)degn, 1.f);
    float4 o0 = make_float4(a0 * inv, a1 * inv, a2 * inv, a3 * inv);
    float4 o1 = make_float4(a4 * inv, a5 * inv, a6 * inv, a7 * inv);
    *(float4*)&out[((size_t)d << 6) + (f8 << 3)] = o0;
    *(float4*)&out[((size_t)d << 6) + (f8 << 3) + 4] = o1;
  }
}

// user side: ushort idx, 4 feats x 4 nbrs per wave-load (deg mean 32)
__device__ __forceinline__ void agg_node_w4(const ushort* __restrict__ feat,
                                            const ushort* __restrict__ idxs,
                                            int s, int degn, float* __restrict__ out,
                                            int d, int lane) {
  int f4 = lane & 15, p = lane >> 4;
  int e = s + degn;
  float a0 = 0.f, a1 = 0.f, a2 = 0.f, a3 = 0.f;
  int i = s;
  for (; i + 16 <= e; i += 16) {
    int s0 = idxs[i + 0 + p];
    int s1 = idxs[i + 4 + p];
    int s2 = idxs[i + 8 + p];
    int s3 = idxs[i + 12 + p];
    uint2 v0 = *(const uint2*)(feat + ((size_t)s0 << 6) + (f4 << 2));
    uint2 v1 = *(const uint2*)(feat + ((size_t)s1 << 6) + (f4 << 2));
    uint2 v2 = *(const uint2*)(feat + ((size_t)s2 << 6) + (f4 << 2));
    uint2 v3 = *(const uint2*)(feat + ((size_t)s3 << 6) + (f4 << 2));
    a0 += __uint_as_float(v0.x << 16); a1 += __uint_as_float(v0.x & 0xffff0000u);
    a2 += __uint_as_float(v0.y << 16); a3 += __uint_as_float(v0.y & 0xffff0000u);
    a0 += __uint_as_float(v1.x << 16); a1 += __uint_as_float(v1.x & 0xffff0000u);
    a2 += __uint_as_float(v1.y << 16); a3 += __uint_as_float(v1.y & 0xffff0000u);
    a0 += __uint_as_float(v2.x << 16); a1 += __uint_as_float(v2.x & 0xffff0000u);
    a2 += __uint_as_float(v2.y << 16); a3 += __uint_as_float(v2.y & 0xffff0000u);
    a0 += __uint_as_float(v3.x << 16); a1 += __uint_as_float(v3.x & 0xffff0000u);
    a2 += __uint_as_float(v3.y << 16); a3 += __uint_as_float(v3.y & 0xffff0000u);
  }
  for (; i < e; i += 4) {
    int ii = i + p;
    bool ok = ii < e;
    int sj = idxs[ok ? ii : i];
    uint2 v = *(const uint2*)(feat + ((size_t)sj << 6) + (f4 << 2));
    if (!ok) { v.x = 0u; v.y = 0u; }
    a0 += __uint_as_float(v.x << 16); a1 += __uint_as_float(v.x & 0xffff0000u);
    a2 += __uint_as_float(v.y << 16); a3 += __uint_as_float(v.y & 0xffff0000u);
  }
  a0 += __shfl_xor(a0, 16, 64); a1 += __shfl_xor(a1, 16, 64);
  a2 += __shfl_xor(a2, 16, 64); a3 += __shfl_xor(a3, 16, 64);
  a0 += __shfl_xor(a0, 32, 64); a1 += __shfl_xor(a1, 32, 64);
  a2 += __shfl_xor(a2, 32, 64); a3 += __shfl_xor(a3, 32, 64);
  if (p == 0) {
    float inv = 1.f / fmaxf((float)degn, 1.f);
    float4 o = make_float4(a0 * inv, a1 * inv, a2 * inv, a3 * inv);
    *(float4*)&out[((size_t)d << 6) + (f4 << 2)] = o;
  }
}

// ---------------- fused mean aggregation (both directions in one grid) ----------------
__global__ void __launch_bounds__(256) k_agg2d(
    int gm,
    const ushort* __restrict__ fM, const int* __restrict__ stM, const int* __restrict__ dgM,
    const int* __restrict__ idxM, float* __restrict__ outM, int nM,
    const ushort* __restrict__ fU, const int* __restrict__ stU, const int* __restrict__ dgU,
    const ushort* __restrict__ idxU, float* __restrict__ outU, int nU) {
  int lane = threadIdx.x & 63;
  if ((int)blockIdx.x < gm) {
    int d = blockIdx.x * 4 + (threadIdx.x >> 6);
    if (d >= nM) return;
    agg_node_w8(fM, idxM, stM[d], dgM[d], outM, d, lane);
  } else {
    int d = (blockIdx.x - gm) * 4 + (threadIdx.x >> 6);
    if (d >= nU) return;
    agg_node_w4(fU, idxU, stU[d], dgU[d], outU, d, lane);
  }
}

// ---------------- fused prep: movie proj (16 rows/blk) + user cvt + packw ----------
static constexpr int PB = NM / 16;                // 1250 proj blocks
static constexpr int CB = (NU * H / 4) / 256;     // 6250 cvt blocks (exact)
__global__ void __launch_bounds__(256) k_prep(
    const float* __restrict__ x, const float* __restrict__ w, const float* __restrict__ b,
    float* __restrict__ out, ushort* __restrict__ outh,
    const float* __restrict__ uemb, ushort* __restrict__ uembh,
    const float* __restrict__ w1, ushort* __restrict__ pw) {
  __shared__ float sw[FD * H];    // 32 KB
  __shared__ float sx[16][FD];    // 8 KB
  int tid = threadIdx.x;
  int blk = blockIdx.x;
  if (blk < PB) {
    int r0 = blk * 16;
    #pragma unroll
    for (int it = 0; it < 8; ++it) {
      int idx = tid + it * 256;
      ((float4*)sw)[idx] = ((const float4*)w)[idx];
    }
    #pragma unroll
    for (int it = 0; it < 2; ++it) {
      int idx = tid + it * 256;
      int row = idx >> 5, q = idx & 31;
      *(float4*)&sx[row][q * 4] = ((const float4*)x)[(size_t)(r0 + row) * 32 + q];
    }
    __syncthreads();
    int col = tid & 63, rg = tid >> 6;
    float bb = b[col];
    float acc[4];
    #pragma unroll
    for (int j = 0; j < 4; ++j) acc[j] = bb;
    #pragma unroll 4
    for (int k4 = 0; k4 < 32; ++k4) {
      float w0 = sw[(k4 * 4 + 0) * H + col], w1_ = sw[(k4 * 4 + 1) * H + col];
      float w2 = sw[(k4 * 4 + 2) * H + col], w3 = sw[(k4 * 4 + 3) * H + col];
      #pragma unroll
      for (int j = 0; j < 4; ++j) {
        float4 a = *(const float4*)&sx[rg + j * 4][k4 * 4];
        acc[j] += a.x * w0 + a.y * w1_ + a.z * w2 + a.w * w3;
      }
    }
    #pragma unroll
    for (int j = 0; j < 4; ++j) {
      size_t o = (size_t)(r0 + rg + j * 4) * H + col;
      out[o] = acc[j];
      outh[o] = bf16rne(acc[j]);
    }
  } else if (blk < PB + CB) {
    int i = (blk - PB) * 256 + tid;
    float4 v = ((const float4*)uemb)[i];
    ushort4 o;
    o.x = bf16rne(v.x); o.y = bf16rne(v.y); o.z = bf16rne(v.z); o.w = bf16rne(v.w);
    ((ushort4*)uembh)[i] = o;
  } else {
    // pack dec_w1 (bf16 hi plane only) into MFMA B-fragment order
    for (int it = 0; it < 4; ++it) {
      int q = tid + it * 256;
      int kt = q >> 8, ct = (q >> 6) & 3, l = q & 63;
      int kg = l >> 4, cg = l & 15;
      #pragma unroll
      for (int j = 0; j < 8; ++j) {
        int k = kt * 32 + kg * 8 + j;
        int c = ct * 16 + cg;
        pw[q * 8 + j] = bf16rne(w1[k * 64 + c]);
      }
    }
  }
}

// ---------------- fused SAGE linear pair, 32 rows/block ----------------
__global__ void __launch_bounds__(256) k_sage32(
    int gm,
    const float* __restrict__ aggM, const float* __restrict__ xdM,
    const float* __restrict__ wlM, const float* __restrict__ wrM,
    const float* __restrict__ blM, float* __restrict__ outfM, ushort* __restrict__ outhM,
    const float* __restrict__ aggU, const float* __restrict__ xdU,
    const float* __restrict__ wlU, const float* __restrict__ wrU,
    const float* __restrict__ blU, float* __restrict__ outfU, ushort* __restrict__ outhU,
    int relu) {
  __shared__ float swl[H * H];   // 16 KB
  __shared__ float swr[H * H];   // 16 KB
  __shared__ float sa[32][H];    // 8 KB
  __shared__ float sd[32][H];    // 8 KB
  int tid = threadIdx.x;
  const float *agg, *xd, *wl, *wr, *bl; float* outf; ushort* outh; int r0;
  if ((int)blockIdx.x < gm) {
    agg = aggM; xd = xdM; wl = wlM; wr = wrM; bl = blM; outf = outfM; outh = outhM;
    r0 = blockIdx.x * 32;
  } else {
    agg = aggU; xd = xdU; wl = wlU; wr = wrU; bl = blU; outf = outfU; outh = outhU;
    r0 = (blockIdx.x - gm) * 32;
  }
  #pragma unroll
  for (int it = 0; it < 4; ++it) {
    int idx = tid + it * 256;
    ((float4*)swl)[idx] = ((const float4*)wl)[idx];
    ((float4*)swr)[idx] = ((const float4*)wr)[idx];
  }
  #pragma unroll
  for (int it = 0; it < 2; ++it) {
    int idx = tid + it * 256;       // 512 float4 = 32 rows x 16
    int row = idx >> 4, q = idx & 15;
    *(float4*)&sa[row][q * 4] = ((const float4*)agg)[(size_t)(r0 + row) * 16 + q];
    *(float4*)&sd[row][q * 4] = ((const float4*)xd)[(size_t)(r0 + row) * 16 + q];
  }
  __syncthreads();
  int col = tid & 63, rg = tid >> 6;
  float b = bl[col];
  float acc[8];
  #pragma unroll
  for (int j = 0; j < 8; ++j) acc[j] = b;
  #pragma unroll 2
  for (int k4 = 0; k4 < 16; ++k4) {
    float w0 = swl[(k4 * 4 + 0) * H + col], w1 = swl[(k4 * 4 + 1) * H + col];
    float w2 = swl[(k4 * 4 + 2) * H + col], w3 = swl[(k4 * 4 + 3) * H + col];
    float v0 = swr[(k4 * 4 + 0) * H + col], v1 = swr[(k4 * 4 + 1) * H + col];
    float v2 = swr[(k4 * 4 + 2) * H + col], v3 = swr[(k4 * 4 + 3) * H + col];
    #pragma unroll
    for (int j = 0; j < 8; ++j) {
      int r = rg + j * 4;
      float4 a = *(const float4*)&sa[r][k4 * 4];
      float4 d = *(const float4*)&sd[r][k4 * 4];
      acc[j] += a.x * w0 + a.y * w1 + a.z * w2 + a.w * w3;
      acc[j] += d.x * v0 + d.y * v1 + d.z * v2 + d.w * v3;
    }
  }
  #pragma unroll
  for (int j = 0; j < 8; ++j) {
    int r = rg + j * 4;
    float v = relu ? fmaxf(acc[j], 0.f) : acc[j];
    size_t o = (size_t)(r0 + r) * H + col;
    if (outf) outf[o] = v;
    if (outh) outh[o] = bf16rne(v);
  }
}

// ---------------- MFMA edge decoder: h1 = relu(x@w1+b1); out = h1@w2+b2 ----------------
// x and w1 both bf16 (hi); w-rounding adds ~2-3e-5 output error (threshold 4.8e-4)
__global__ void __launch_bounds__(256) k_dec_mfma(
    const ushort* __restrict__ uhi, const ushort* __restrict__ mhi,
    const int* __restrict__ lu, const int* __restrict__ lm,
    const ushort* __restrict__ pw,
    const float* __restrict__ b1, const float* __restrict__ w2,
    const float* __restrict__ b2, float* __restrict__ out) {
  __shared__ ushort sB[16 * 64 * 8];  // 16 KB packed w1 fragments (hi plane)
  int tid = threadIdx.x;
  #pragma unroll
  for (int it = 0; it < 4; ++it) {
    int idx = tid + it * 256;
    ((float4*)sB)[idx] = ((const float4*)pw)[idx];
  }
  __syncthreads();
  int l = tid & 63, w = tid >> 6;
  int cg = l & 15, kg = l >> 4;
  float w2f[4], b1f[4];
  #pragma unroll
  for (int ct = 0; ct < 4; ++ct) {
    w2f[ct] = w2[ct * 16 + cg];
    b1f[ct] = b1[ct * 16 + cg];
  }
  float b2v = b2[0];
  for (int t = 0; t < 4; ++t) {
    int Lb = blockIdx.x * 256 + w * 64 + t * 16;
    int lab = min(Lb + cg, NL - 1);
    int nu = lu[lab], nm = lm[lab];
    const size_t ub = (size_t)nu * 64 + kg * 8;
    const size_t mb = (size_t)nm * 64 + kg * 8;
    short8v ah[4];
    ah[0] = *(const short8v*)(uhi + ub);
    ah[1] = *(const short8v*)(uhi + ub + 32);
    ah[2] = *(const short8v*)(mhi + mb);
    ah[3] = *(const short8v*)(mhi + mb + 32);
    f32x4 acc[4];
    #pragma unroll
    for (int ct = 0; ct < 4; ++ct) acc[ct] = (f32x4){b1f[ct], b1f[ct], b1f[ct], b1f[ct]};
    #pragma unroll
    for (int kt = 0; kt < 4; ++kt) {
      #pragma unroll
      for (int ct = 0; ct < 4; ++ct) {
        const int f = kt * 4 + ct;
        short8v bh = *(const short8v*)&sB[(size_t)(f * 64 + l) * 8];
        acc[ct] = __builtin_amdgcn_mfma_f32_16x16x32_bf16(ah[kt], bh, acc[ct], 0, 0, 0);
      }
    }
    float p[4];
    #pragma unroll
    for (int r = 0; r < 4; ++r) {
      p[r] = fmaxf(acc[0][r], 0.f) * w2f[0] + fmaxf(acc[1][r], 0.f) * w2f[1] +
             fmaxf(acc[2][r], 0.f) * w2f[2] + fmaxf(acc[3][r], 0.f) * w2f[3];
    }
    #pragma unroll
    for (int m = 8; m >= 1; m >>= 1) {
      #pragma unroll
      for (int r = 0; r < 4; ++r) p[r] += __shfl_xor(p[r], m, 64);
    }
    if (cg == 0) {
      #pragma unroll
      for (int r = 0; r < 4; ++r) {
        int row = Lb + kg * 4 + r;
        if (row < NL) out[row] = p[r] + b2v;
      }
    }
  }
}

extern "C" void kernel_launch(void* const* d_in, const int* in_sizes, int n_in,
                              void* d_out, int out_size, void* d_ws, size_t ws_size,
                              hipStream_t stream) {
  const float* movie_x  = (const float*)d_in[0];
  const int*   esrc     = (const int*)d_in[1];
  const int*   edst     = (const int*)d_in[2];
  const int*   lu       = (const int*)d_in[3];
  const int*   lm       = (const int*)d_in[4];
  const float* user_emb = (const float*)d_in[5];
  const float* proj_w   = (const float*)d_in[6];
  const float* proj_b   = (const float*)d_in[7];
  const float* dec_w1   = (const float*)d_in[8];
  const float* dec_b1   = (const float*)d_in[9];
  const float* dec_w2   = (const float*)d_in[10];
  const float* dec_b2   = (const float*)d_in[11];
  const float* w1_um_l  = (const float*)d_in[12];
  const float* b1_um_l  = (const float*)d_in[13];
  const float* w1_um_r  = (const float*)d_in[14];
  const float* w1_mu_l  = (const float*)d_in[15];
  const float* b1_mu_l  = (const float*)d_in[16];
  const float* w1_mu_r  = (const float*)d_in[17];
  const float* w2_um_l  = (const float*)d_in[18];
  const float* b2_um_l  = (const float*)d_in[19];
  const float* w2_um_r  = (const float*)d_in[20];
  const float* w2_mu_l  = (const float*)d_in[21];
  const float* b2_mu_l  = (const float*)d_in[22];
  const float* w2_mu_r  = (const float*)d_in[23];

  char* ws = (char*)d_ws;
  size_t off = 0;
  auto alloc = [&](size_t bytes) {
    void* p = ws + off;
    off = (off + bytes + 255) & ~(size_t)255;
    return p;
  };
  float* movie0   = (float*)alloc((size_t)NM * H * 4);
  float* movie1   = (float*)alloc((size_t)NM * H * 4);
  // union: pairs_m+pairs_u (build phase) alias user1+agg regions (written after build)
  float* user1    = (float*)alloc((size_t)NU * H * 4);   // 25.6 MB
  float* agg_m    = (float*)alloc((size_t)NM * H * 4);
  float* agg_u    = (float*)alloc((size_t)NU * H * 4);   // 25.6 MB
  unsigned* pairs_m = (unsigned*)user1;                  // 20.5 MB
  unsigned* pairs_u = pairs_m + (size_t)NBM * CAP_M;     // 19.2 MB, spills into agg region (dead)
  ushort* uembh   = (ushort*)alloc((size_t)NU * H * 2);  // user_emb bf16
  ushort* movie0h = (ushort*)alloc((size_t)NM * H * 2);
  ushort* movie1h = (ushort*)alloc((size_t)NM * H * 2);
  ushort* user1h  = (ushort*)alloc((size_t)NU * H * 2);
  ushort* uhi     = (ushort*)alloc((size_t)NU * H * 2);  // conv2 user output (bf16)
  ushort* mhi     = (ushort*)alloc((size_t)NM * H * 2);  // conv2 movie output (bf16)
  int* st_m      = (int*)alloc((size_t)NM * 4);          // per-node start (gapped CSR)
  int* st_u      = (int*)alloc((size_t)NU * 4);
  int* dg_m      = (int*)alloc((size_t)NM * 4);          // per-node degree
  int* dg_u      = (int*)alloc((size_t)NU * 4);
  int* bcur_m    = (int*)alloc((size_t)NBM * 4);
  int* bcur_u    = (int*)alloc((size_t)NBU * 4);
  int* su_by_m   = (int*)alloc((size_t)NBM * CAP_M * 4);    // 20.5 MB gapped adjacency (int)
  ushort* sm_by_u = (ushort*)alloc((size_t)NBU * CAP_U * 2); // 9.6 MB gapped adjacency (u16)
  ushort* pw     = (ushort*)alloc((size_t)16 * 64 * 8 * 2);  // 16 KB (hi plane only)
  (void)ws_size; (void)in_sizes; (void)n_in; (void)out_size;

  // ---- build gapped per-node CSR: fixed-cap buckets -> per-side bin -> in-bucket sort --
  k_binit2<<<(NBU + 255) / 256, 256, 0, stream>>>(bcur_m, bcur_u);
  int nbPerSide = (NE + B3C - 1) / B3C;   // 196
  k_bin3<<<2 * nbPerSide, 256, 0, stream>>>(esrc, edst, bcur_m, bcur_u,
                                            pairs_m, pairs_u, nbPerSide);
  k_sortb4<<<NBM + NBU, 256, 0, stream>>>(pairs_m, pairs_u, bcur_m, bcur_u,
                                          st_m, dg_m, su_by_m, st_u, dg_u, sm_by_u);

  // fused prep: movie0 = movie_x @ proj_w + proj_b (f32+bf16); user_emb->bf16; packw
  k_prep<<<PB + CB + 1, 256, 0, stream>>>(movie_x, proj_w, proj_b, movie0, movie0h,
                                          user_emb, uembh, dec_w1, pw);

  const int GAM = NM / 4, GAU = NU / 4;        // agg grids
  const int GSM = NM / 32, GSU = NU / 32;      // sage grids

  // conv1
  k_agg2d<<<GAM + GAU, 256, 0, stream>>>(GAM,
      uembh,   st_m, dg_m, su_by_m, agg_m, NM,
      movie0h, st_u, dg_u, sm_by_u, agg_u, NU);
  k_sage32<<<GSM + GSU, 256, 0, stream>>>(GSM,
      agg_m, movie0,   w1_um_l, w1_um_r, b1_um_l, movie1, movie1h,
      agg_u, user_emb, w1_mu_l, w1_mu_r, b1_mu_l, user1,  user1h, 1);

  // conv2 (writes decoder bf16 planes directly)
  k_agg2d<<<GAM + GAU, 256, 0, stream>>>(GAM,
      user1h,  st_m, dg_m, su_by_m, agg_m, NM,
      movie1h, st_u, dg_u, sm_by_u, agg_u, NU);
  k_sage32<<<GSM + GSU, 256, 0, stream>>>(GSM,
      agg_m, movie1, w2_um_l, w2_um_r, b2_um_l, (float*)nullptr, mhi,
      agg_u, user1,  w2_mu_l, w2_mu_r, b2_mu_l, (float*)nullptr, uhi, 0);

  // decoder
  k_dec_mfma<<<(NL + 255) / 256, 256, 0, stream>>>(uhi, mhi, lu, lm, pw,
                                                   dec_b1, dec_w2, dec_b2, (float*)d_out);
}

// Round 15
// 454.108 us; speedup vs baseline: 1.0937x; 1.0099x over previous
//
#include <hip/hip_runtime.h>

static constexpr int NU = 100000;
static constexpr int NM = 20000;
static constexpr int NE = 3200000;
static constexpr int NL = 1000000;
static constexpr int FD = 128;
static constexpr int H  = 64;

// bucket geometry
static constexpr int MBK = 16;                    // movies per bucket
static constexpr int UBK = 64;                    // users per bucket
static constexpr int NBM = NM / MBK;              // 1250
static constexpr int NBU = (NU + UBK - 1) / UBK;  // 1563
// fixed bucket capacities (mean 2560/2048, sigma ~51/45 -> +30/+22 sigma slack)
static constexpr int CAP_M = 4096;
static constexpr int CAP_U = 3072;
static constexpr int B3C = 16384;                 // edges per bin block (per side)

typedef __attribute__((ext_vector_type(8))) short short8v;
typedef __attribute__((ext_vector_type(4))) float f32x4;

__device__ __forceinline__ ushort bf16rne(float x) {
  unsigned u = __float_as_uint(x);
  return (ushort)((u + 0x7fffu + ((u >> 16) & 1u)) >> 16);
}
__device__ __forceinline__ float bf2f(ushort h) {
  return __uint_as_float((unsigned)h << 16);
}

// ---------------- init bucket cursors to fixed-capacity bases ----------------
__global__ void k_binit2(int* __restrict__ bcur_m, int* __restrict__ bcur_u) {
  int i = blockIdx.x * 256 + threadIdx.x;
  if (i < NBM) bcur_m[i] = i * CAP_M;
  if (i < NBU) bcur_u[i] = i * CAP_U;
}

// ---------------- per-side binned ranked scatter (simple 2-pass) ----------------
// movie-side entry: (d&15)<<17 | s      user-side entry: (s&63)<<15 | d
__global__ void __launch_bounds__(256) k_bin3(
    const int* __restrict__ esrc, const int* __restrict__ edst,
    int* __restrict__ bcur_m, int* __restrict__ bcur_u,
    unsigned* __restrict__ pairs_m, unsigned* __restrict__ pairs_u, int nbPerSide) {
  __shared__ int cnt[NBU];    // 6.1 KB (worst side)
  __shared__ int base[NBU];
  int tid = threadIdx.x;
  bool um = (int)blockIdx.x < nbPerSide;
  int cb = um ? blockIdx.x : blockIdx.x - nbPerSide;
  int nbs = um ? NBM : NBU;
  int sh = um ? 4 : 6;
  int* bcur = um ? bcur_m : bcur_u;
  unsigned* pairs = um ? pairs_m : pairs_u;
  const int* keys = um ? edst : esrc;
  const int* vals = um ? esrc : edst;
  int e0 = cb * B3C, e1 = min(e0 + B3C, NE);
  for (int i = tid; i < nbs; i += 256) cnt[i] = 0;
  __syncthreads();
  // pass 1: count buckets (int4 reads, key array only)
  for (int e = e0 + (tid << 2); e < e1; e += 1024) {
    int4 k = *(const int4*)(keys + e);
    atomicAdd(&cnt[k.x >> sh], 1);
    atomicAdd(&cnt[k.y >> sh], 1);
    atomicAdd(&cnt[k.z >> sh], 1);
    atomicAdd(&cnt[k.w >> sh], 1);
  }
  __syncthreads();
  // reserve global space per touched bucket, reset counters to rank
  for (int i = tid; i < nbs; i += 256) {
    int c = cnt[i];
    if (c > 0) base[i] = atomicAdd(&bcur[i], c);
    cnt[i] = 0;
  }
  __syncthreads();
  // pass 2: ranked write
  int lsh = um ? 17 : 15;
  unsigned lmask = um ? 15u : 63u;
  for (int e = e0 + (tid << 2); e < e1; e += 1024) {
    int4 k = *(const int4*)(keys + e);
    int4 v = *(const int4*)(vals + e);
    int ks[4] = {k.x, k.y, k.z, k.w};
    int vs[4] = {v.x, v.y, v.z, v.w};
    #pragma unroll
    for (int j = 0; j < 4; ++j) {
      int b = ks[j] >> sh;
      int r = atomicAdd(&cnt[b], 1);
      pairs[base[b] + r] = (((unsigned)ks[j] & lmask) << lsh) | (unsigned)vs[j];
    }
  }
}

// ---------------- per-bucket counting sort -> gapped per-node CSR ----------------
__global__ void __launch_bounds__(256) k_sortb4(
    const unsigned* __restrict__ pairs_m, const unsigned* __restrict__ pairs_u,
    const int* __restrict__ bcur_m, const int* __restrict__ bcur_u,
    int* __restrict__ st_m, int* __restrict__ dg_m, int* __restrict__ out_m,
    int* __restrict__ st_u, int* __restrict__ dg_u, ushort* __restrict__ out_u) {
  __shared__ int cnt[64];
  __shared__ int cbase[64];
  const unsigned* pairs; const int* bcur; int* start; int* deg;
  int b, npb, shift, cap, n; unsigned mask;
  bool um = (int)blockIdx.x < NBM;
  if (um) {
    pairs = pairs_m; bcur = bcur_m; start = st_m; deg = dg_m;
    b = blockIdx.x; npb = MBK; shift = 17; mask = 0x1FFFFu; cap = CAP_M; n = NM;
  } else {
    pairs = pairs_u; bcur = bcur_u; start = st_u; deg = dg_u;
    b = blockIdx.x - NBM; npb = UBK; shift = 15; mask = 0x7FFFu; cap = CAP_U; n = NU;
  }
  int tid = threadIdx.x;
  if (tid < 64) cnt[tid] = 0;
  __syncthreads();
  int e0 = b * cap, e1 = bcur[b];
  for (int e = e0 + tid; e < e1; e += 256) atomicAdd(&cnt[pairs[e] >> shift], 1);
  __syncthreads();
  if (tid < 64) {
    int c = cnt[tid];
    int v = c;
    #pragma unroll
    for (int off = 1; off < 64; off <<= 1) {
      int t = __shfl_up(v, off, 64);
      if (tid >= off) v += t;
    }
    int basee = e0 + v - c;
    cbase[tid] = basee;
    int node = b * npb + tid;
    if (tid < npb && node < n) { start[node] = basee; deg[node] = c; }
    cnt[tid] = 0;
  }
  __syncthreads();
  for (int e = e0 + tid; e < e1; e += 256) {
    unsigned v = pairs[e];
    int loc = (int)(v >> shift);
    int r = atomicAdd(&cnt[loc], 1);
    if (um) out_m[cbase[loc] + r] = (int)(v & mask);
    else    out_u[cbase[loc] + r] = (ushort)(v & mask);
  }
}

// ---------------- aggregation node helpers (24 VGPR shape; bf16 output) ----------
#define ACC4(vv)                                                           \
  a0 += __uint_as_float((vv).x << 16); a1 += __uint_as_float((vv).x & 0xffff0000u); \
  a2 += __uint_as_float((vv).y << 16); a3 += __uint_as_float((vv).y & 0xffff0000u); \
  a4 += __uint_as_float((vv).z << 16); a5 += __uint_as_float((vv).z & 0xffff0000u); \
  a6 += __uint_as_float((vv).w << 16); a7 += __uint_as_float((vv).w & 0xffff0000u);

// movie side: int idx, 8 feats x 8 nbrs per wave iter (deg mean 160)
__device__ __forceinline__ void agg_node_w8(const ushort* __restrict__ feat,
                                            const int* __restrict__ idxs,
                                            int s, int degn, ushort* __restrict__ out,
                                            int d, int lane) {
  int f8 = lane & 7, p = lane >> 3;
  int e = s + degn;
  float a0 = 0.f, a1 = 0.f, a2 = 0.f, a3 = 0.f, a4 = 0.f, a5 = 0.f, a6 = 0.f, a7 = 0.f;
  int i = s;
  for (; i + 32 <= e; i += 32) {
    int s0 = idxs[i + 0 + p];
    int s1 = idxs[i + 8 + p];
    int s2 = idxs[i + 16 + p];
    int s3 = idxs[i + 24 + p];
    uint4 v0 = *(const uint4*)(feat + ((size_t)s0 << 6) + (f8 << 3));
    uint4 v1 = *(const uint4*)(feat + ((size_t)s1 << 6) + (f8 << 3));
    uint4 v2 = *(const uint4*)(feat + ((size_t)s2 << 6) + (f8 << 3));
    uint4 v3 = *(const uint4*)(feat + ((size_t)s3 << 6) + (f8 << 3));
    ACC4(v0) ACC4(v1) ACC4(v2) ACC4(v3)
  }
  for (; i < e; i += 8) {
    int ii = i + p;
    bool ok = ii < e;
    int sj = idxs[ok ? ii : i];
    uint4 v = *(const uint4*)(feat + ((size_t)sj << 6) + (f8 << 3));
    if (!ok) { v.x = 0u; v.y = 0u; v.z = 0u; v.w = 0u; }
    ACC4(v)
  }
  #pragma unroll
  for (int m = 8; m < 64; m <<= 1) {
    a0 += __shfl_xor(a0, m, 64); a1 += __shfl_xor(a1, m, 64);
    a2 += __shfl_xor(a2, m, 64); a3 += __shfl_xor(a3, m, 64);
    a4 += __shfl_xor(a4, m, 64); a5 += __shfl_xor(a5, m, 64);
    a6 += __shfl_xor(a6, m, 64); a7 += __shfl_xor(a7, m, 64);
  }
  if (p == 0) {
    float inv = 1.f / fmaxf((float)degn, 1.f);
    short8v o;
    o[0] = (short)bf16rne(a0 * inv); o[1] = (short)bf16rne(a1 * inv);
    o[2] = (short)bf16rne(a2 * inv); o[3] = (short)bf16rne(a3 * inv);
    o[4] = (short)bf16rne(a4 * inv); o[5] = (short)bf16rne(a5 * inv);
    o[6] = (short)bf16rne(a6 * inv); o[7] = (short)bf16rne(a7 * inv);
    *(short8v*)&out[((size_t)d << 6) + (f8 << 3)] = o;
  }
}

// user side: ushort idx, 4 feats x 4 nbrs per wave-load (deg mean 32)
__device__ __forceinline__ void agg_node_w4(const ushort* __restrict__ feat,
                                            const ushort* __restrict__ idxs,
                                            int s, int degn, ushort* __restrict__ out,
                                            int d, int lane) {
  int f4 = lane & 15, p = lane >> 4;
  int e = s + degn;
  float a0 = 0.f, a1 = 0.f, a2 = 0.f, a3 = 0.f;
  int i = s;
  for (; i + 16 <= e; i += 16) {
    int s0 = idxs[i + 0 + p];
    int s1 = idxs[i + 4 + p];
    int s2 = idxs[i + 8 + p];
    int s3 = idxs[i + 12 + p];
    uint2 v0 = *(const uint2*)(feat + ((size_t)s0 << 6) + (f4 << 2));
    uint2 v1 = *(const uint2*)(feat + ((size_t)s1 << 6) + (f4 << 2));
    uint2 v2 = *(const uint2*)(feat + ((size_t)s2 << 6) + (f4 << 2));
    uint2 v3 = *(const uint2*)(feat + ((size_t)s3 << 6) + (f4 << 2));
    a0 += __uint_as_float(v0.x << 16); a1 += __uint_as_float(v0.x & 0xffff0000u);
    a2 += __uint_as_float(v0.y << 16); a3 += __uint_as_float(v0.y & 0xffff0000u);
    a0 += __uint_as_float(v1.x << 16); a1 += __uint_as_float(v1.x & 0xffff0000u);
    a2 += __uint_as_float(v1.y << 16); a3 += __uint_as_float(v1.y & 0xffff0000u);
    a0 += __uint_as_float(v2.x << 16); a1 += __uint_as_float(v2.x & 0xffff0000u);
    a2 += __uint_as_float(v2.y << 16); a3 += __uint_as_float(v2.y & 0xffff0000u);
    a0 += __uint_as_float(v3.x << 16); a1 += __uint_as_float(v3.x & 0xffff0000u);
    a2 += __uint_as_float(v3.y << 16); a3 += __uint_as_float(v3.y & 0xffff0000u);
  }
  for (; i < e; i += 4) {
    int ii = i + p;
    bool ok = ii < e;
    int sj = idxs[ok ? ii : i];
    uint2 v = *(const uint2*)(feat + ((size_t)sj << 6) + (f4 << 2));
    if (!ok) { v.x = 0u; v.y = 0u; }
    a0 += __uint_as_float(v.x << 16); a1 += __uint_as_float(v.x & 0xffff0000u);
    a2 += __uint_as_float(v.y << 16); a3 += __uint_as_float(v.y & 0xffff0000u);
  }
  a0 += __shfl_xor(a0, 16, 64); a1 += __shfl_xor(a1, 16, 64);
  a2 += __shfl_xor(a2, 16, 64); a3 += __shfl_xor(a3, 16, 64);
  a0 += __shfl_xor(a0, 32, 64); a1 += __shfl_xor(a1, 32, 64);
  a2 += __shfl_xor(a2, 32, 64); a3 += __shfl_xor(a3, 32, 64);
  if (p == 0) {
    float inv = 1.f / fmaxf((float)degn, 1.f);
    ushort4 o = make_ushort4(bf16rne(a0 * inv), bf16rne(a1 * inv),
                             bf16rne(a2 * inv), bf16rne(a3 * inv));
    *(ushort4*)&out[((size_t)d << 6) + (f4 << 2)] = o;
  }
}

// ---------------- fused mean aggregation (both directions in one grid) ----------------
__global__ void __launch_bounds__(256) k_agg2d(
    int gm,
    const ushort* __restrict__ fM, const int* __restrict__ stM, const int* __restrict__ dgM,
    const int* __restrict__ idxM, ushort* __restrict__ outM, int nM,
    const ushort* __restrict__ fU, const int* __restrict__ stU, const int* __restrict__ dgU,
    const ushort* __restrict__ idxU, ushort* __restrict__ outU, int nU) {
  int lane = threadIdx.x & 63;
  if ((int)blockIdx.x < gm) {
    int d = blockIdx.x * 4 + (threadIdx.x >> 6);
    if (d >= nM) return;
    agg_node_w8(fM, idxM, stM[d], dgM[d], outM, d, lane);
  } else {
    int d = (blockIdx.x - gm) * 4 + (threadIdx.x >> 6);
    if (d >= nU) return;
    agg_node_w4(fU, idxU, stU[d], dgU[d], outU, d, lane);
  }
}

// ---------------- fused prep: movie proj (16 rows/blk, bf16 out) + user cvt + packw ----
static constexpr int PB = NM / 16;                // 1250 proj blocks
static constexpr int CB = (NU * H / 4) / 256;     // 6250 cvt blocks (exact)
__global__ void __launch_bounds__(256) k_prep(
    const float* __restrict__ x, const float* __restrict__ w, const float* __restrict__ b,
    ushort* __restrict__ outh,
    const float* __restrict__ uemb, ushort* __restrict__ uembh,
    const float* __restrict__ w1, ushort* __restrict__ pw) {
  __shared__ float sw[FD * H];    // 32 KB
  __shared__ float sx[16][FD];    // 8 KB
  int tid = threadIdx.x;
  int blk = blockIdx.x;
  if (blk < PB) {
    int r0 = blk * 16;
    #pragma unroll
    for (int it = 0; it < 8; ++it) {
      int idx = tid + it * 256;
      ((float4*)sw)[idx] = ((const float4*)w)[idx];
    }
    #pragma unroll
    for (int it = 0; it < 2; ++it) {
      int idx = tid + it * 256;
      int row = idx >> 5, q = idx & 31;
      *(float4*)&sx[row][q * 4] = ((const float4*)x)[(size_t)(r0 + row) * 32 + q];
    }
    __syncthreads();
    int col = tid & 63, rg = tid >> 6;
    float bb = b[col];
    float acc[4];
    #pragma unroll
    for (int j = 0; j < 4; ++j) acc[j] = bb;
    #pragma unroll 4
    for (int k4 = 0; k4 < 32; ++k4) {
      float w0 = sw[(k4 * 4 + 0) * H + col], w1_ = sw[(k4 * 4 + 1) * H + col];
      float w2 = sw[(k4 * 4 + 2) * H + col], w3 = sw[(k4 * 4 + 3) * H + col];
      #pragma unroll
      for (int j = 0; j < 4; ++j) {
        float4 a = *(const float4*)&sx[rg + j * 4][k4 * 4];
        acc[j] += a.x * w0 + a.y * w1_ + a.z * w2 + a.w * w3;
      }
    }
    #pragma unroll
    for (int j = 0; j < 4; ++j)
      outh[(size_t)(r0 + rg + j * 4) * H + col] = bf16rne(acc[j]);
  } else if (blk < PB + CB) {
    int i = (blk - PB) * 256 + tid;
    float4 v = ((const float4*)uemb)[i];
    ushort4 o;
    o.x = bf16rne(v.x); o.y = bf16rne(v.y); o.z = bf16rne(v.z); o.w = bf16rne(v.w);
    ((ushort4*)uembh)[i] = o;
  } else {
    // pack dec_w1 (bf16 hi plane) into MFMA B-fragment order
    for (int it = 0; it < 4; ++it) {
      int q = tid + it * 256;
      int kt = q >> 8, ct = (q >> 6) & 3, l = q & 63;
      int kg = l >> 4, cg = l & 15;
      #pragma unroll
      for (int j = 0; j < 8; ++j) {
        int k = kt * 32 + kg * 8 + j;
        int c = ct * 16 + cg;
        pw[q * 8 + j] = bf16rne(w1[k * 64 + c]);
      }
    }
  }
}

// ---------------- fused SAGE linear pair, 32 rows/block, bf16 in / bf16 out --------
__global__ void __launch_bounds__(256) k_sage32(
    int gm,
    const ushort* __restrict__ aggM, const ushort* __restrict__ xdM,
    const float* __restrict__ wlM, const float* __restrict__ wrM,
    const float* __restrict__ blM, ushort* __restrict__ outM,
    const ushort* __restrict__ aggU, const ushort* __restrict__ xdU,
    const float* __restrict__ wlU, const float* __restrict__ wrU,
    const float* __restrict__ blU, ushort* __restrict__ outU,
    int relu) {
  __shared__ float swl[H * H];   // 16 KB
  __shared__ float swr[H * H];   // 16 KB
  __shared__ float sa[32][H];    // 8 KB
  __shared__ float sd[32][H];    // 8 KB
  int tid = threadIdx.x;
  const ushort *agg, *xd; const float *wl, *wr, *bl; ushort* outh; int r0;
  if ((int)blockIdx.x < gm) {
    agg = aggM; xd = xdM; wl = wlM; wr = wrM; bl = blM; outh = outM;
    r0 = blockIdx.x * 32;
  } else {
    agg = aggU; xd = xdU; wl = wlU; wr = wrU; bl = blU; outh = outU;
    r0 = (blockIdx.x - gm) * 32;
  }
  #pragma unroll
  for (int it = 0; it < 4; ++it) {
    int idx = tid + it * 256;
    ((float4*)swl)[idx] = ((const float4*)wl)[idx];
    ((float4*)swr)[idx] = ((const float4*)wr)[idx];
  }
  {
    int row = tid >> 3, q = tid & 7;   // 256 threads = 32 rows x 8 groups of 8 bf16
    short8v va = *(const short8v*)&agg[(size_t)(r0 + row) * H + q * 8];
    short8v vd = *(const short8v*)&xd[(size_t)(r0 + row) * H + q * 8];
    #pragma unroll
    for (int j = 0; j < 8; ++j) {
      sa[row][q * 8 + j] = bf2f((ushort)va[j]);
      sd[row][q * 8 + j] = bf2f((ushort)vd[j]);
    }
  }
  __syncthreads();
  int col = tid & 63, rg = tid >> 6;
  float b = bl[col];
  float acc[8];
  #pragma unroll
  for (int j = 0; j < 8; ++j) acc[j] = b;
  #pragma unroll 2
  for (int k4 = 0; k4 < 16; ++k4) {
    float w0 = swl[(k4 * 4 + 0) * H + col], w1 = swl[(k4 * 4 + 1) * H + col];
    float w2 = swl[(k4 * 4 + 2) * H + col], w3 = swl[(k4 * 4 + 3) * H + col];
    float v0 = swr[(k4 * 4 + 0) * H + col], v1 = swr[(k4 * 4 + 1) * H + col];
    float v2 = swr[(k4 * 4 + 2) * H + col], v3 = swr[(k4 * 4 + 3) * H + col];
    #pragma unroll
    for (int j = 0; j < 8; ++j) {
      int r = rg + j * 4;
      float4 a = *(const float4*)&sa[r][k4 * 4];
      float4 d = *(const float4*)&sd[r][k4 * 4];
      acc[j] += a.x * w0 + a.y * w1 + a.z * w2 + a.w * w3;
      acc[j] += d.x * v0 + d.y * v1 + d.z * v2 + d.w * v3;
    }
  }
  #pragma unroll
  for (int j = 0; j < 8; ++j) {
    int r = rg + j * 4;
    float v = relu ? fmaxf(acc[j], 0.f) : acc[j];
    outh[(size_t)(r0 + r) * H + col] = bf16rne(v);
  }
}

// ---------------- MFMA edge decoder: h1 = relu(x@w1+b1); out = h1@w2+b2 ----------------
__global__ void __launch_bounds__(256) k_dec_mfma(
    const ushort* __restrict__ uhi, const ushort* __restrict__ mhi,
    const int* __restrict__ lu, const int* __restrict__ lm,
    const ushort* __restrict__ pw,
    const float* __restrict__ b1, const float* __restrict__ w2,
    const float* __restrict__ b2, float* __restrict__ out) {
  __shared__ ushort sB[16 * 64 * 8];  // 16 KB packed w1 fragments (hi plane)
  int tid = threadIdx.x;
  #pragma unroll
  for (int it = 0; it < 4; ++it) {
    int idx = tid + it * 256;
    ((float4*)sB)[idx] = ((const float4*)pw)[idx];
  }
  __syncthreads();
  int l = tid & 63, w = tid >> 6;
  int cg = l & 15, kg = l >> 4;
  float w2f[4], b1f[4];
  #pragma unroll
  for (int ct = 0; ct < 4; ++ct) {
    w2f[ct] = w2[ct * 16 + cg];
    b1f[ct] = b1[ct * 16 + cg];
  }
  float b2v = b2[0];
  for (int t = 0; t < 4; ++t) {
    int Lb = blockIdx.x * 256 + w * 64 + t * 16;
    int lab = min(Lb + cg, NL - 1);
    int nu = lu[lab], nm = lm[lab];
    const size_t ub = (size_t)nu * 64 + kg * 8;
    const size_t mb = (size_t)nm * 64 + kg * 8;
    short8v ah[4];
    ah[0] = *(const short8v*)(uhi + ub);
    ah[1] = *(const short8v*)(uhi + ub + 32);
    ah[2] = *(const short8v*)(mhi + mb);
    ah[3] = *(const short8v*)(mhi + mb + 32);
    f32x4 acc[4];
    #pragma unroll
    for (int ct = 0; ct < 4; ++ct) acc[ct] = (f32x4){b1f[ct], b1f[ct], b1f[ct], b1f[ct]};
    #pragma unroll
    for (int kt = 0; kt < 4; ++kt) {
      #pragma unroll
      for (int ct = 0; ct < 4; ++ct) {
        const int f = kt * 4 + ct;
        short8v bh = *(const short8v*)&sB[(size_t)(f * 64 + l) * 8];
        acc[ct] = __builtin_amdgcn_mfma_f32_16x16x32_bf16(ah[kt], bh, acc[ct], 0, 0, 0);
      }
    }
    float p[4];
    #pragma unroll
    for (int r = 0; r < 4; ++r) {
      p[r] = fmaxf(acc[0][r], 0.f) * w2f[0] + fmaxf(acc[1][r], 0.f) * w2f[1] +
             fmaxf(acc[2][r], 0.f) * w2f[2] + fmaxf(acc[3][r], 0.f) * w2f[3];
    }
    #pragma unroll
    for (int m = 8; m >= 1; m >>= 1) {
      #pragma unroll
      for (int r = 0; r < 4; ++r) p[r] += __shfl_xor(p[r], m, 64);
    }
    if (cg == 0) {
      #pragma unroll
      for (int r = 0; r < 4; ++r) {
        int row = Lb + kg * 4 + r;
        if (row < NL) out[row] = p[r] + b2v;
      }
    }
  }
}

extern "C" void kernel_launch(void* const* d_in, const int* in_sizes, int n_in,
                              void* d_out, int out_size, void* d_ws, size_t ws_size,
                              hipStream_t stream) {
  const float* movie_x  = (const float*)d_in[0];
  const int*   esrc     = (const int*)d_in[1];
  const int*   edst     = (const int*)d_in[2];
  const int*   lu       = (const int*)d_in[3];
  const int*   lm       = (const int*)d_in[4];
  const float* user_emb = (const float*)d_in[5];
  const float* proj_w   = (const float*)d_in[6];
  const float* proj_b   = (const float*)d_in[7];
  const float* dec_w1   = (const float*)d_in[8];
  const float* dec_b1   = (const float*)d_in[9];
  const float* dec_w2   = (const float*)d_in[10];
  const float* dec_b2   = (const float*)d_in[11];
  const float* w1_um_l  = (const float*)d_in[12];
  const float* b1_um_l  = (const float*)d_in[13];
  const float* w1_um_r  = (const float*)d_in[14];
  const float* w1_mu_l  = (const float*)d_in[15];
  const float* b1_mu_l  = (const float*)d_in[16];
  const float* w1_mu_r  = (const float*)d_in[17];
  const float* w2_um_l  = (const float*)d_in[18];
  const float* b2_um_l  = (const float*)d_in[19];
  const float* w2_um_r  = (const float*)d_in[20];
  const float* w2_mu_l  = (const float*)d_in[21];
  const float* b2_mu_l  = (const float*)d_in[22];
  const float* w2_mu_r  = (const float*)d_in[23];

  char* ws = (char*)d_ws;
  size_t off = 0;
  auto alloc = [&](size_t bytes) {
    void* p = ws + off;
    off = (off + bytes + 255) & ~(size_t)255;
    return p;
  };
  // pairs region (build phase) aliases agg bf16 arrays (conv phase)
  unsigned* pairs_m = (unsigned*)alloc((size_t)(NBM * CAP_M + NBU * CAP_U) * 4); // 39.7 MB
  unsigned* pairs_u = pairs_m + (size_t)NBM * CAP_M;
  ushort* agg_mh  = (ushort*)pairs_m;            // 2.56 MB
  ushort* agg_uh  = agg_mh + (size_t)NM * H;     // 12.8 MB (fits in pairs region)
  ushort* uembh   = (ushort*)alloc((size_t)NU * H * 2);  // user_emb bf16
  ushort* movie0h = (ushort*)alloc((size_t)NM * H * 2);
  ushort* movie1h = (ushort*)alloc((size_t)NM * H * 2);
  ushort* user1h  = (ushort*)alloc((size_t)NU * H * 2);
  ushort* uhi     = (ushort*)alloc((size_t)NU * H * 2);  // conv2 user output (bf16)
  ushort* mhi     = (ushort*)alloc((size_t)NM * H * 2);  // conv2 movie output (bf16)
  int* st_m      = (int*)alloc((size_t)NM * 4);          // per-node start (gapped CSR)
  int* st_u      = (int*)alloc((size_t)NU * 4);
  int* dg_m      = (int*)alloc((size_t)NM * 4);          // per-node degree
  int* dg_u      = (int*)alloc((size_t)NU * 4);
  int* bcur_m    = (int*)alloc((size_t)NBM * 4);
  int* bcur_u    = (int*)alloc((size_t)NBU * 4);
  int* su_by_m   = (int*)alloc((size_t)NBM * CAP_M * 4);    // 20.5 MB gapped adjacency (int)
  ushort* sm_by_u = (ushort*)alloc((size_t)NBU * CAP_U * 2); // 9.6 MB gapped adjacency (u16)
  ushort* pw     = (ushort*)alloc((size_t)16 * 64 * 8 * 2);  // 16 KB (hi plane only)
  (void)ws_size; (void)in_sizes; (void)n_in; (void)out_size;

  // ---- build gapped per-node CSR: fixed-cap buckets -> per-side bin -> in-bucket sort --
  k_binit2<<<(NBU + 255) / 256, 256, 0, stream>>>(bcur_m, bcur_u);
  int nbPerSide = (NE + B3C - 1) / B3C;   // 196
  k_bin3<<<2 * nbPerSide, 256, 0, stream>>>(esrc, edst, bcur_m, bcur_u,
                                            pairs_m, pairs_u, nbPerSide);
  k_sortb4<<<NBM + NBU, 256, 0, stream>>>(pairs_m, pairs_u, bcur_m, bcur_u,
                                          st_m, dg_m, su_by_m, st_u, dg_u, sm_by_u);

  // fused prep: movie0h = bf16(movie_x @ proj_w + proj_b); user_emb->bf16; packw
  k_prep<<<PB + CB + 1, 256, 0, stream>>>(movie_x, proj_w, proj_b, movie0h,
                                          user_emb, uembh, dec_w1, pw);

  const int GAM = NM / 4, GAU = NU / 4;        // agg grids
  const int GSM = NM / 32, GSU = NU / 32;      // sage grids

  // conv1 (pairs dead after sortb4; agg arrays alias them)
  k_agg2d<<<GAM + GAU, 256, 0, stream>>>(GAM,
      uembh,   st_m, dg_m, su_by_m, agg_mh, NM,
      movie0h, st_u, dg_u, sm_by_u, agg_uh, NU);
  k_sage32<<<GSM + GSU, 256, 0, stream>>>(GSM,
      agg_mh, movie0h, w1_um_l, w1_um_r, b1_um_l, movie1h,
      agg_uh, uembh,   w1_mu_l, w1_mu_r, b1_mu_l, user1h, 1);

  // conv2 (writes decoder bf16 planes directly)
  k_agg2d<<<GAM + GAU, 256, 0, stream>>>(GAM,
      user1h,  st_m, dg_m, su_by_m, agg_mh, NM,
      movie1h, st_u, dg_u, sm_by_u, agg_uh, NU);
  k_sage32<<<GSM + GSU, 256, 0, stream>>>(GSM,
      agg_mh, movie1h, w2_um_l, w2_um_r, b2_um_l, mhi,
      agg_uh, user1h,  w2_mu_l, w2_mu_r, b2_mu_l, uhi, 0);

  // decoder
  k_dec_mfma<<<(NL + 255) / 256, 256, 0, stream>>>(uhi, mhi, lu, lm, pw,
                                                   dec_b1, dec_w2, dec_b2, (float*)d_out);
}

// Round 16
// 447.351 us; speedup vs baseline: 1.1102x; 1.0151x over previous
//
#include <hip/hip_runtime.h>

static constexpr int NU = 100000;
static constexpr int NM = 20000;
static constexpr int NE = 3200000;
static constexpr int NL = 1000000;
static constexpr int FD = 128;
static constexpr int H  = 64;

// bucket geometry
static constexpr int MBK = 16;                    // movies per bucket
static constexpr int UBK = 64;                    // users per bucket
static constexpr int NBM = NM / MBK;              // 1250
static constexpr int NBU = (NU + UBK - 1) / UBK;  // 1563
// fixed bucket capacities (mean 2560/2048, sigma ~51/45 -> +30/+22 sigma slack)
static constexpr int CAP_M = 4096;
static constexpr int CAP_U = 3072;
static constexpr int B3C = 16384;                 // edges per bin block (per side)

typedef __attribute__((ext_vector_type(8))) short short8v;
typedef __attribute__((ext_vector_type(4))) float f32x4;

__device__ __forceinline__ ushort bf16rne(float x) {
  unsigned u = __float_as_uint(x);
  return (ushort)((u + 0x7fffu + ((u >> 16) & 1u)) >> 16);
}
__device__ __forceinline__ float bf2f(ushort h) {
  return __uint_as_float((unsigned)h << 16);
}

// ---------------- fused: per-side binned scatter + prep (proj/cvt/packw) ----------
// bin role   : blocks [0, 2*nbPerSide)        - 12.5 KB LDS (cnt+base)
// proj role  : next PB blocks                 - 40 KB LDS (sw+sx)
// cvt role   : next CB blocks                 - no LDS
// packw role : last block                     - no LDS
static constexpr int PB = NM / 16;                // 1250 proj blocks
static constexpr int CB = (NU * H / 4) / 256;     // 6250 cvt blocks (exact)
__global__ void __launch_bounds__(256) k_fuse1(
    const int* __restrict__ esrc, const int* __restrict__ edst,
    int* __restrict__ bcur_m, int* __restrict__ bcur_u,
    unsigned* __restrict__ pairs_m, unsigned* __restrict__ pairs_u, int nbPerSide,
    const float* __restrict__ x, const float* __restrict__ w, const float* __restrict__ b,
    ushort* __restrict__ outh,
    const float* __restrict__ uemb, ushort* __restrict__ uembh,
    const float* __restrict__ w1, ushort* __restrict__ pw) {
  extern __shared__ char smem[];
  int tid = threadIdx.x;
  int blk = blockIdx.x;
  if (blk < 2 * nbPerSide) {
    // ---- bin role: simple 2-pass ranked scatter, fixed-cap bucket bases ----
    int* cnt = (int*)smem;          // NBU ints
    int* base = cnt + NBU;          // NBU ints
    bool um = blk < nbPerSide;
    int cb = um ? blk : blk - nbPerSide;
    int nbs = um ? NBM : NBU;
    int sh = um ? 4 : 6;
    int cap = um ? CAP_M : CAP_U;
    int* bcur = um ? bcur_m : bcur_u;
    unsigned* pairs = um ? pairs_m : pairs_u;
    const int* keys = um ? edst : esrc;
    const int* vals = um ? esrc : edst;
    int e0 = cb * B3C, e1 = min(e0 + B3C, NE);
    for (int i = tid; i < nbs; i += 256) cnt[i] = 0;
    __syncthreads();
    for (int e = e0 + (tid << 2); e < e1; e += 1024) {
      int4 k = *(const int4*)(keys + e);
      atomicAdd(&cnt[k.x >> sh], 1);
      atomicAdd(&cnt[k.y >> sh], 1);
      atomicAdd(&cnt[k.z >> sh], 1);
      atomicAdd(&cnt[k.w >> sh], 1);
    }
    __syncthreads();
    for (int i = tid; i < nbs; i += 256) {
      int c = cnt[i];
      if (c > 0) base[i] = i * cap + atomicAdd(&bcur[i], c);
      cnt[i] = 0;
    }
    __syncthreads();
    int lsh = um ? 17 : 15;
    unsigned lmask = um ? 15u : 63u;
    for (int e = e0 + (tid << 2); e < e1; e += 1024) {
      int4 k = *(const int4*)(keys + e);
      int4 v = *(const int4*)(vals + e);
      int ks[4] = {k.x, k.y, k.z, k.w};
      int vs[4] = {v.x, v.y, v.z, v.w};
      #pragma unroll
      for (int j = 0; j < 4; ++j) {
        int bb = ks[j] >> sh;
        int r = atomicAdd(&cnt[bb], 1);
        pairs[base[bb] + r] = (((unsigned)ks[j] & lmask) << lsh) | (unsigned)vs[j];
      }
    }
  } else if (blk < 2 * nbPerSide + PB) {
    // ---- proj role: movie0h = bf16(movie_x @ proj_w + proj_b), 16 rows/block ----
    float* sw = (float*)smem;               // FD*H floats = 32 KB
    float (*sx)[FD] = (float(*)[FD])(sw + FD * H);  // 16*FD floats = 8 KB
    int r0 = (blk - 2 * nbPerSide) * 16;
    #pragma unroll
    for (int it = 0; it < 8; ++it) {
      int idx = tid + it * 256;
      ((float4*)sw)[idx] = ((const float4*)w)[idx];
    }
    #pragma unroll
    for (int it = 0; it < 2; ++it) {
      int idx = tid + it * 256;
      int row = idx >> 5, q = idx & 31;
      *(float4*)&sx[row][q * 4] = ((const float4*)x)[(size_t)(r0 + row) * 32 + q];
    }
    __syncthreads();
    int col = tid & 63, rg = tid >> 6;
    float bb = b[col];
    float acc[4];
    #pragma unroll
    for (int j = 0; j < 4; ++j) acc[j] = bb;
    #pragma unroll 4
    for (int k4 = 0; k4 < 32; ++k4) {
      float w0 = sw[(k4 * 4 + 0) * H + col], w1_ = sw[(k4 * 4 + 1) * H + col];
      float w2 = sw[(k4 * 4 + 2) * H + col], w3 = sw[(k4 * 4 + 3) * H + col];
      #pragma unroll
      for (int j = 0; j < 4; ++j) {
        float4 a = *(const float4*)&sx[rg + j * 4][k4 * 4];
        acc[j] += a.x * w0 + a.y * w1_ + a.z * w2 + a.w * w3;
      }
    }
    #pragma unroll
    for (int j = 0; j < 4; ++j)
      outh[(size_t)(r0 + rg + j * 4) * H + col] = bf16rne(acc[j]);
  } else if (blk < 2 * nbPerSide + PB + CB) {
    // ---- cvt role: user_emb -> bf16 ----
    int i = (blk - 2 * nbPerSide - PB) * 256 + tid;
    float4 v = ((const float4*)uemb)[i];
    ushort4 o;
    o.x = bf16rne(v.x); o.y = bf16rne(v.y); o.z = bf16rne(v.z); o.w = bf16rne(v.w);
    ((ushort4*)uembh)[i] = o;
  } else {
    // ---- packw role: dec_w1 bf16 hi plane into MFMA B-fragment order ----
    for (int it = 0; it < 4; ++it) {
      int q = tid + it * 256;
      int kt = q >> 8, ct = (q >> 6) & 3, l = q & 63;
      int kg = l >> 4, cg = l & 15;
      #pragma unroll
      for (int j = 0; j < 8; ++j) {
        int k = kt * 32 + kg * 8 + j;
        int c = ct * 16 + cg;
        pw[q * 8 + j] = bf16rne(w1[k * 64 + c]);
      }
    }
  }
}

// ---------------- per-bucket counting sort -> gapped per-node CSR ----------------
__global__ void __launch_bounds__(256) k_sortb4(
    const unsigned* __restrict__ pairs_m, const unsigned* __restrict__ pairs_u,
    const int* __restrict__ bcur_m, const int* __restrict__ bcur_u,
    int* __restrict__ st_m, int* __restrict__ dg_m, int* __restrict__ out_m,
    int* __restrict__ st_u, int* __restrict__ dg_u, ushort* __restrict__ out_u) {
  __shared__ int cnt[64];
  __shared__ int cbase[64];
  const unsigned* pairs; const int* bcur; int* start; int* deg;
  int b, npb, shift, cap, n; unsigned mask;
  bool um = (int)blockIdx.x < NBM;
  if (um) {
    pairs = pairs_m; bcur = bcur_m; start = st_m; deg = dg_m;
    b = blockIdx.x; npb = MBK; shift = 17; mask = 0x1FFFFu; cap = CAP_M; n = NM;
  } else {
    pairs = pairs_u; bcur = bcur_u; start = st_u; deg = dg_u;
    b = blockIdx.x - NBM; npb = UBK; shift = 15; mask = 0x7FFFu; cap = CAP_U; n = NU;
  }
  int tid = threadIdx.x;
  if (tid < 64) cnt[tid] = 0;
  __syncthreads();
  int e0 = b * cap, e1 = e0 + bcur[b];
  for (int e = e0 + tid; e < e1; e += 256) atomicAdd(&cnt[pairs[e] >> shift], 1);
  __syncthreads();
  if (tid < 64) {
    int c = cnt[tid];
    int v = c;
    #pragma unroll
    for (int off = 1; off < 64; off <<= 1) {
      int t = __shfl_up(v, off, 64);
      if (tid >= off) v += t;
    }
    int basee = e0 + v - c;
    cbase[tid] = basee;
    int node = b * npb + tid;
    if (tid < npb && node < n) { start[node] = basee; deg[node] = c; }
    cnt[tid] = 0;
  }
  __syncthreads();
  for (int e = e0 + tid; e < e1; e += 256) {
    unsigned v = pairs[e];
    int loc = (int)(v >> shift);
    int r = atomicAdd(&cnt[loc], 1);
    if (um) out_m[cbase[loc] + r] = (int)(v & mask);
    else    out_u[cbase[loc] + r] = (ushort)(v & mask);
  }
}

// ---------------- aggregation node helpers (24 VGPR shape; bf16 output) ----------
#define ACC4(vv)                                                           \
  a0 += __uint_as_float((vv).x << 16); a1 += __uint_as_float((vv).x & 0xffff0000u); \
  a2 += __uint_as_float((vv).y << 16); a3 += __uint_as_float((vv).y & 0xffff0000u); \
  a4 += __uint_as_float((vv).z << 16); a5 += __uint_as_float((vv).z & 0xffff0000u); \
  a6 += __uint_as_float((vv).w << 16); a7 += __uint_as_float((vv).w & 0xffff0000u);

// movie side: int idx, 8 feats x 8 nbrs per wave iter (deg mean 160)
__device__ __forceinline__ void agg_node_w8(const ushort* __restrict__ feat,
                                            const int* __restrict__ idxs,
                                            int s, int degn, ushort* __restrict__ out,
                                            int d, int lane) {
  int f8 = lane & 7, p = lane >> 3;
  int e = s + degn;
  float a0 = 0.f, a1 = 0.f, a2 = 0.f, a3 = 0.f, a4 = 0.f, a5 = 0.f, a6 = 0.f, a7 = 0.f;
  int i = s;
  for (; i + 32 <= e; i += 32) {
    int s0 = idxs[i + 0 + p];
    int s1 = idxs[i + 8 + p];
    int s2 = idxs[i + 16 + p];
    int s3 = idxs[i + 24 + p];
    uint4 v0 = *(const uint4*)(feat + ((size_t)s0 << 6) + (f8 << 3));
    uint4 v1 = *(const uint4*)(feat + ((size_t)s1 << 6) + (f8 << 3));
    uint4 v2 = *(const uint4*)(feat + ((size_t)s2 << 6) + (f8 << 3));
    uint4 v3 = *(const uint4*)(feat + ((size_t)s3 << 6) + (f8 << 3));
    ACC4(v0) ACC4(v1) ACC4(v2) ACC4(v3)
  }
  for (; i < e; i += 8) {
    int ii = i + p;
    bool ok = ii < e;
    int sj = idxs[ok ? ii : i];
    uint4 v = *(const uint4*)(feat + ((size_t)sj << 6) + (f8 << 3));
    if (!ok) { v.x = 0u; v.y = 0u; v.z = 0u; v.w = 0u; }
    ACC4(v)
  }
  #pragma unroll
  for (int m = 8; m < 64; m <<= 1) {
    a0 += __shfl_xor(a0, m, 64); a1 += __shfl_xor(a1, m, 64);
    a2 += __shfl_xor(a2, m, 64); a3 += __shfl_xor(a3, m, 64);
    a4 += __shfl_xor(a4, m, 64); a5 += __shfl_xor(a5, m, 64);
    a6 += __shfl_xor(a6, m, 64); a7 += __shfl_xor(a7, m, 64);
  }
  if (p == 0) {
    float inv = 1.f / fmaxf((float)degn, 1.f);
    short8v o;
    o[0] = (short)bf16rne(a0 * inv); o[1] = (short)bf16rne(a1 * inv);
    o[2] = (short)bf16rne(a2 * inv); o[3] = (short)bf16rne(a3 * inv);
    o[4] = (short)bf16rne(a4 * inv); o[5] = (short)bf16rne(a5 * inv);
    o[6] = (short)bf16rne(a6 * inv); o[7] = (short)bf16rne(a7 * inv);
    *(short8v*)&out[((size_t)d << 6) + (f8 << 3)] = o;
  }
}

// user side: ushort idx, 4 feats x 4 nbrs per wave-load (deg mean 32)
__device__ __forceinline__ void agg_node_w4(const ushort* __restrict__ feat,
                                            const ushort* __restrict__ idxs,
                                            int s, int degn, ushort* __restrict__ out,
                                            int d, int lane) {
  int f4 = lane & 15, p = lane >> 4;
  int e = s + degn;
  float a0 = 0.f, a1 = 0.f, a2 = 0.f, a3 = 0.f;
  int i = s;
  for (; i + 16 <= e; i += 16) {
    int s0 = idxs[i + 0 + p];
    int s1 = idxs[i + 4 + p];
    int s2 = idxs[i + 8 + p];
    int s3 = idxs[i + 12 + p];
    uint2 v0 = *(const uint2*)(feat + ((size_t)s0 << 6) + (f4 << 2));
    uint2 v1 = *(const uint2*)(feat + ((size_t)s1 << 6) + (f4 << 2));
    uint2 v2 = *(const uint2*)(feat + ((size_t)s2 << 6) + (f4 << 2));
    uint2 v3 = *(const uint2*)(feat + ((size_t)s3 << 6) + (f4 << 2));
    a0 += __uint_as_float(v0.x << 16); a1 += __uint_as_float(v0.x & 0xffff0000u);
    a2 += __uint_as_float(v0.y << 16); a3 += __uint_as_float(v0.y & 0xffff0000u);
    a0 += __uint_as_float(v1.x << 16); a1 += __uint_as_float(v1.x & 0xffff0000u);
    a2 += __uint_as_float(v1.y << 16); a3 += __uint_as_float(v1.y & 0xffff0000u);
    a0 += __uint_as_float(v2.x << 16); a1 += __uint_as_float(v2.x & 0xffff0000u);
    a2 += __uint_as_float(v2.y << 16); a3 += __uint_as_float(v2.y & 0xffff0000u);
    a0 += __uint_as_float(v3.x << 16); a1 += __uint_as_float(v3.x & 0xffff0000u);
    a2 += __uint_as_float(v3.y << 16); a3 += __uint_as_float(v3.y & 0xffff0000u);
  }
  for (; i < e; i += 4) {
    int ii = i + p;
    bool ok = ii < e;
    int sj = idxs[ok ? ii : i];
    uint2 v = *(const uint2*)(feat + ((size_t)sj << 6) + (f4 << 2));
    if (!ok) { v.x = 0u; v.y = 0u; }
    a0 += __uint_as_float(v.x << 16); a1 += __uint_as_float(v.x & 0xffff0000u);
    a2 += __uint_as_float(v.y << 16); a3 += __uint_as_float(v.y & 0xffff0000u);
  }
  a0 += __shfl_xor(a0, 16, 64); a1 += __shfl_xor(a1, 16, 64);
  a2 += __shfl_xor(a2, 16, 64); a3 += __shfl_xor(a3, 16, 64);
  a0 += __shfl_xor(a0, 32, 64); a1 += __shfl_xor(a1, 32, 64);
  a2 += __shfl_xor(a2, 32, 64); a3 += __shfl_xor(a3, 32, 64);
  if (p == 0) {
    float inv = 1.f / fmaxf((float)degn, 1.f);
    ushort4 o = make_ushort4(bf16rne(a0 * inv), bf16rne(a1 * inv),
                             bf16rne(a2 * inv), bf16rne(a3 * inv));
    *(ushort4*)&out[((size_t)d << 6) + (f4 << 2)] = o;
  }
}

// ---------------- fused mean aggregation (both directions in one grid) ----------------
__global__ void __launch_bounds__(256) k_agg2d(
    int gm,
    const ushort* __restrict__ fM, const int* __restrict__ stM, const int* __restrict__ dgM,
    const int* __restrict__ idxM, ushort* __restrict__ outM, int nM,
    const ushort* __restrict__ fU, const int* __restrict__ stU, const int* __restrict__ dgU,
    const ushort* __restrict__ idxU, ushort* __restrict__ outU, int nU) {
  int lane = threadIdx.x & 63;
  if ((int)blockIdx.x < gm) {
    int d = blockIdx.x * 4 + (threadIdx.x >> 6);
    if (d >= nM) return;
    agg_node_w8(fM, idxM, stM[d], dgM[d], outM, d, lane);
  } else {
    int d = (blockIdx.x - gm) * 4 + (threadIdx.x >> 6);
    if (d >= nU) return;
    agg_node_w4(fU, idxU, stU[d], dgU[d], outU, d, lane);
  }
}

// ---------------- fused SAGE linear pair, 32 rows/block, bf16 in / bf16 out --------
__global__ void __launch_bounds__(256) k_sage32(
    int gm,
    const ushort* __restrict__ aggM, const ushort* __restrict__ xdM,
    const float* __restrict__ wlM, const float* __restrict__ wrM,
    const float* __restrict__ blM, ushort* __restrict__ outM,
    const ushort* __restrict__ aggU, const ushort* __restrict__ xdU,
    const float* __restrict__ wlU, const float* __restrict__ wrU,
    const float* __restrict__ blU, ushort* __restrict__ outU,
    int relu) {
  __shared__ float swl[H * H];   // 16 KB
  __shared__ float swr[H * H];   // 16 KB
  __shared__ float sa[32][H];    // 8 KB
  __shared__ float sd[32][H];    // 8 KB
  int tid = threadIdx.x;
  const ushort *agg, *xd; const float *wl, *wr, *bl; ushort* outh; int r0;
  if ((int)blockIdx.x < gm) {
    agg = aggM; xd = xdM; wl = wlM; wr = wrM; bl = blM; outh = outM;
    r0 = blockIdx.x * 32;
  } else {
    agg = aggU; xd = xdU; wl = wlU; wr = wrU; bl = blU; outh = outU;
    r0 = (blockIdx.x - gm) * 32;
  }
  #pragma unroll
  for (int it = 0; it < 4; ++it) {
    int idx = tid + it * 256;
    ((float4*)swl)[idx] = ((const float4*)wl)[idx];
    ((float4*)swr)[idx] = ((const float4*)wr)[idx];
  }
  {
    int row = tid >> 3, q = tid & 7;   // 256 threads = 32 rows x 8 groups of 8 bf16
    short8v va = *(const short8v*)&agg[(size_t)(r0 + row) * H + q * 8];
    short8v vd = *(const short8v*)&xd[(size_t)(r0 + row) * H + q * 8];
    #pragma unroll
    for (int j = 0; j < 8; ++j) {
      sa[row][q * 8 + j] = bf2f((ushort)va[j]);
      sd[row][q * 8 + j] = bf2f((ushort)vd[j]);
    }
  }
  __syncthreads();
  int col = tid & 63, rg = tid >> 6;
  float b = bl[col];
  float acc[8];
  #pragma unroll
  for (int j = 0; j < 8; ++j) acc[j] = b;
  #pragma unroll 2
  for (int k4 = 0; k4 < 16; ++k4) {
    float w0 = swl[(k4 * 4 + 0) * H + col], w1 = swl[(k4 * 4 + 1) * H + col];
    float w2 = swl[(k4 * 4 + 2) * H + col], w3 = swl[(k4 * 4 + 3) * H + col];
    float v0 = swr[(k4 * 4 + 0) * H + col], v1 = swr[(k4 * 4 + 1) * H + col];
    float v2 = swr[(k4 * 4 + 2) * H + col], v3 = swr[(k4 * 4 + 3) * H + col];
    #pragma unroll
    for (int j = 0; j < 8; ++j) {
      int r = rg + j * 4;
      float4 a = *(const float4*)&sa[r][k4 * 4];
      float4 d = *(const float4*)&sd[r][k4 * 4];
      acc[j] += a.x * w0 + a.y * w1 + a.z * w2 + a.w * w3;
      acc[j] += d.x * v0 + d.y * v1 + d.z * v2 + d.w * v3;
    }
  }
  #pragma unroll
  for (int j = 0; j < 8; ++j) {
    int r = rg + j * 4;
    float v = relu ? fmaxf(acc[j], 0.f) : acc[j];
    outh[(size_t)(r0 + r) * H + col] = bf16rne(v);
  }
}

// ---------------- MFMA edge decoder: h1 = relu(x@w1+b1); out = h1@w2+b2 ----------------
__global__ void __launch_bounds__(256) k_dec_mfma(
    const ushort* __restrict__ uhi, const ushort* __restrict__ mhi,
    const int* __restrict__ lu, const int* __restrict__ lm,
    const ushort* __restrict__ pw,
    const float* __restrict__ b1, const float* __restrict__ w2,
    const float* __restrict__ b2, float* __restrict__ out) {
  __shared__ ushort sB[16 * 64 * 8];  // 16 KB packed w1 fragments (hi plane)
  int tid = threadIdx.x;
  #pragma unroll
  for (int it = 0; it < 4; ++it) {
    int idx = tid + it * 256;
    ((float4*)sB)[idx] = ((const float4*)pw)[idx];
  }
  __syncthreads();
  int l = tid & 63, w = tid >> 6;
  int cg = l & 15, kg = l >> 4;
  float w2f[4], b1f[4];
  #pragma unroll
  for (int ct = 0; ct < 4; ++ct) {
    w2f[ct] = w2[ct * 16 + cg];
    b1f[ct] = b1[ct * 16 + cg];
  }
  float b2v = b2[0];
  for (int t = 0; t < 4; ++t) {
    int Lb = blockIdx.x * 256 + w * 64 + t * 16;
    int lab = min(Lb + cg, NL - 1);
    int nu = lu[lab], nm = lm[lab];
    const size_t ub = (size_t)nu * 64 + kg * 8;
    const size_t mb = (size_t)nm * 64 + kg * 8;
    short8v ah[4];
    ah[0] = *(const short8v*)(uhi + ub);
    ah[1] = *(const short8v*)(uhi + ub + 32);
    ah[2] = *(const short8v*)(mhi + mb);
    ah[3] = *(const short8v*)(mhi + mb + 32);
    f32x4 acc[4];
    #pragma unroll
    for (int ct = 0; ct < 4; ++ct) acc[ct] = (f32x4){b1f[ct], b1f[ct], b1f[ct], b1f[ct]};
    #pragma unroll
    for (int kt = 0; kt < 4; ++kt) {
      #pragma unroll
      for (int ct = 0; ct < 4; ++ct) {
        const int f = kt * 4 + ct;
        short8v bh = *(const short8v*)&sB[(size_t)(f * 64 + l) * 8];
        acc[ct] = __builtin_amdgcn_mfma_f32_16x16x32_bf16(ah[kt], bh, acc[ct], 0, 0, 0);
      }
    }
    float p[4];
    #pragma unroll
    for (int r = 0; r < 4; ++r) {
      p[r] = fmaxf(acc[0][r], 0.f) * w2f[0] + fmaxf(acc[1][r], 0.f) * w2f[1] +
             fmaxf(acc[2][r], 0.f) * w2f[2] + fmaxf(acc[3][r], 0.f) * w2f[3];
    }
    #pragma unroll
    for (int m = 8; m >= 1; m >>= 1) {
      #pragma unroll
      for (int r = 0; r < 4; ++r) p[r] += __shfl_xor(p[r], m, 64);
    }
    if (cg == 0) {
      #pragma unroll
      for (int r = 0; r < 4; ++r) {
        int row = Lb + kg * 4 + r;
        if (row < NL) out[row] = p[r] + b2v;
      }
    }
  }
}

extern "C" void kernel_launch(void* const* d_in, const int* in_sizes, int n_in,
                              void* d_out, int out_size, void* d_ws, size_t ws_size,
                              hipStream_t stream) {
  const float* movie_x  = (const float*)d_in[0];
  const int*   esrc     = (const int*)d_in[1];
  const int*   edst     = (const int*)d_in[2];
  const int*   lu       = (const int*)d_in[3];
  const int*   lm       = (const int*)d_in[4];
  const float* user_emb = (const float*)d_in[5];
  const float* proj_w   = (const float*)d_in[6];
  const float* proj_b   = (const float*)d_in[7];
  const float* dec_w1   = (const float*)d_in[8];
  const float* dec_b1   = (const float*)d_in[9];
  const float* dec_w2   = (const float*)d_in[10];
  const float* dec_b2   = (const float*)d_in[11];
  const float* w1_um_l  = (const float*)d_in[12];
  const float* b1_um_l  = (const float*)d_in[13];
  const float* w1_um_r  = (const float*)d_in[14];
  const float* w1_mu_l  = (const float*)d_in[15];
  const float* b1_mu_l  = (const float*)d_in[16];
  const float* w1_mu_r  = (const float*)d_in[17];
  const float* w2_um_l  = (const float*)d_in[18];
  const float* b2_um_l  = (const float*)d_in[19];
  const float* w2_um_r  = (const float*)d_in[20];
  const float* w2_mu_l  = (const float*)d_in[21];
  const float* b2_mu_l  = (const float*)d_in[22];
  const float* w2_mu_r  = (const float*)d_in[23];

  char* ws = (char*)d_ws;
  size_t off = 0;
  auto alloc = [&](size_t bytes) {
    void* p = ws + off;
    off = (off + bytes + 255) & ~(size_t)255;
    return p;
  };
  // pairs region (build phase) aliases agg bf16 arrays (conv phase)
  unsigned* pairs_m = (unsigned*)alloc((size_t)(NBM * CAP_M + NBU * CAP_U) * 4); // 39.7 MB
  unsigned* pairs_u = pairs_m + (size_t)NBM * CAP_M;
  ushort* agg_mh  = (ushort*)pairs_m;            // 2.56 MB
  ushort* agg_uh  = agg_mh + (size_t)NM * H;     // 12.8 MB (fits in pairs region)
  ushort* uembh   = (ushort*)alloc((size_t)NU * H * 2);  // user_emb bf16
  ushort* movie0h = (ushort*)alloc((size_t)NM * H * 2);
  ushort* movie1h = (ushort*)alloc((size_t)NM * H * 2);
  ushort* user1h  = (ushort*)alloc((size_t)NU * H * 2);
  ushort* uhi     = (ushort*)alloc((size_t)NU * H * 2);  // conv2 user output (bf16)
  ushort* mhi     = (ushort*)alloc((size_t)NM * H * 2);  // conv2 movie output (bf16)
  int* st_m      = (int*)alloc((size_t)NM * 4);          // per-node start (gapped CSR)
  int* st_u      = (int*)alloc((size_t)NU * 4);
  int* dg_m      = (int*)alloc((size_t)NM * 4);          // per-node degree
  int* dg_u      = (int*)alloc((size_t)NU * 4);
  int* bcur_m    = (int*)alloc((size_t)(NBM + NBU) * 4); // contiguous cursor block
  int* bcur_u    = bcur_m + NBM;
  int* su_by_m   = (int*)alloc((size_t)NBM * CAP_M * 4);    // 20.5 MB gapped adjacency (int)
  ushort* sm_by_u = (ushort*)alloc((size_t)NBU * CAP_U * 2); // 9.6 MB gapped adjacency (u16)
  ushort* pw     = (ushort*)alloc((size_t)16 * 64 * 8 * 2);  // 16 KB (hi plane only)
  (void)ws_size; (void)in_sizes; (void)n_in; (void)out_size;

  // ---- fused build + prep: cursors to 0; bin (fixed-cap base folded) + proj/cvt/packw --
  hipMemsetAsync(bcur_m, 0, (size_t)(NBM + NBU) * 4, stream);
  int nbPerSide = (NE + B3C - 1) / B3C;   // 196
  int fuseBlocks = 2 * nbPerSide + PB + CB + 1;
  k_fuse1<<<fuseBlocks, 256, 40960, stream>>>(
      esrc, edst, bcur_m, bcur_u, pairs_m, pairs_u, nbPerSide,
      movie_x, proj_w, proj_b, movie0h, user_emb, uembh, dec_w1, pw);
  k_sortb4<<<NBM + NBU, 256, 0, stream>>>(pairs_m, pairs_u, bcur_m, bcur_u,
                                          st_m, dg_m, su_by_m, st_u, dg_u, sm_by_u);

  const int GAM = NM / 4, GAU = NU / 4;        // agg grids
  const int GSM = NM / 32, GSU = NU / 32;      // sage grids

  // conv1 (pairs dead after sortb4; agg arrays alias them)
  k_agg2d<<<GAM + GAU, 256, 0, stream>>>(GAM,
      uembh,   st_m, dg_m, su_by_m, agg_mh, NM,
      movie0h, st_u, dg_u, sm_by_u, agg_uh, NU);
  k_sage32<<<GSM + GSU, 256, 0, stream>>>(GSM,
      agg_mh, movie0h, w1_um_l, w1_um_r, b1_um_l, movie1h,
      agg_uh, uembh,   w1_mu_l, w1_mu_r, b1_mu_l, user1h, 1);

  // conv2 (writes decoder bf16 planes directly)
  k_agg2d<<<GAM + GAU, 256, 0, stream>>>(GAM,
      user1h,  st_m, dg_m, su_by_m, agg_mh, NM,
      movie1h, st_u, dg_u, sm_by_u, agg_uh, NU);
  k_sage32<<<GSM + GSU, 256, 0, stream>>>(GSM,
      agg_mh, movie1h, w2_um_l, w2_um_r, b2_um_l, mhi,
      agg_uh, user1h,  w2_mu_l, w2_mu_r, b2_mu_l, uhi, 0);

  // decoder
  k_dec_mfma<<<(NL + 255) / 256, 256, 0, stream>>>(uhi, mhi, lu, lm, pw,
                                                   dec_b1, dec_w2, dec_b2, (float*)d_out);
}